// Round 1
// baseline (4519.638 us; speedup 1.0000x reference)
//
#include <hip/hip_runtime.h>
#include <hip/hip_bf16.h>

#define NN 50000      // nodes
#define NE 800000     // edges
// C=32 channels, K=64 spline kernels, H=8 heads, DH=4, M=32 features

// ---------------- K1: histogram of dst ----------------
__global__ void k_hist(const int* __restrict__ ei, int* __restrict__ cnt) {
    int e = blockIdx.x * 256 + threadIdx.x;   // grid exact: 3125*256 = 800000
    atomicAdd(&cnt[ei[NE + e]], 1);
}

// ---------------- K2: exclusive scan (single block) ----------------
__global__ void __launch_bounds__(1024) k_scan(const int* __restrict__ cnt,
                                               int* __restrict__ rowptr,
                                               int* __restrict__ fill,
                                               float* __restrict__ degf) {
    __shared__ int sums[1024];
    int tid = threadIdx.x;
    int carry = 0;
    for (int base = 0; base < NN; base += 8192) {
        int i0 = base + tid * 8;
        int v[8], pre[8], s = 0;
#pragma unroll
        for (int j = 0; j < 8; j++) {
            int i = i0 + j;
            v[j] = (i < NN) ? cnt[i] : 0;
            pre[j] = s; s += v[j];
        }
        sums[tid] = s;
        __syncthreads();
        for (int off = 1; off < 1024; off <<= 1) {
            int x = (tid >= off) ? sums[tid - off] : 0;
            __syncthreads();
            sums[tid] += x;
            __syncthreads();
        }
        int excl = sums[tid] - s;
        int total = sums[1023];
#pragma unroll
        for (int j = 0; j < 8; j++) {
            int i = i0 + j;
            if (i < NN) {
                int st = carry + excl + pre[j];
                rowptr[i] = st;
                fill[i]   = st;
                degf[i]   = (float)(v[j] > 0 ? v[j] : 1);
                if (i == NN - 1) rowptr[NN] = st + v[j];
            }
        }
        carry += total;
        __syncthreads();
    }
}

// ---------------- K3: scatter edges into CSR order ----------------
__global__ void k_scatter(const int* __restrict__ ei, const float* __restrict__ attr,
                          int* __restrict__ fill, float4* __restrict__ sedge) {
    int e = blockIdx.x * 256 + threadIdx.x;
    int src = ei[e], dst = ei[NE + e];
    int pos = atomicAdd(&fill[dst], 1);
    float4 r;
    r.x = __int_as_float(src);
    r.y = attr[e * 3 + 0]; r.z = attr[e * 3 + 1]; r.w = attr[e * 3 + 2];
    sedge[pos] = r;
}

// ---------------- K4: fused SplineConv + leaky + BN-stats ----------------
// 8 nodes/block, 512 threads. LDS buf layout: [k][t][c ^ ((k&7)<<2)]
__global__ void __launch_bounds__(512) k_spline(
        const float* __restrict__ xin, const int* __restrict__ rowptr,
        const float4* __restrict__ sedge, const float* __restrict__ degf,
        const float* __restrict__ wsp, const float* __restrict__ root,
        const float* __restrict__ bias, float* __restrict__ out,
        float* __restrict__ stats) {
    __shared__ __align__(16) float buf[16384];  // 64k * 8t * 32c
    __shared__ __align__(16) float xt[8][32];
    __shared__ __align__(16) float scr[2048];
    __shared__ float scr2[64];
    int tid = threadIdx.x;
    int wave = tid >> 6, lane = tid & 63;
    for (int i = tid; i < 16384; i += 512) buf[i] = 0.f;
    if (tid < 64) scr2[tid] = 0.f;
    int nb = blockIdx.x * 8;                    // NN % 8 == 0, always in-bounds
    if (tid < 256) {
        int t = tid >> 5, c = tid & 31;
        xt[t][c] = xin[(nb + t) * 32 + c];
    }
    __syncthreads();
    // -------- phase A: per-node edge accumulation into LDS --------
    {
        int t = wave;
        int n = nb + t;
        int rs = rowptr[n], re = rowptr[n + 1];
        int ch = lane & 31, hi = lane >> 5;
        for (int e = rs; e < re; e++) {
            float4 ed = sedge[e];
            int src = __float_as_int(ed.x);
            float p0 = ed.y * 3.f, p1 = ed.z * 3.f, p2 = ed.w * 3.f;
            float f0 = fmaxf(fminf(floorf(p0), 2.f), 0.f);
            float f1 = fmaxf(fminf(floorf(p1), 2.f), 0.f);
            float f2 = fmaxf(fminf(floorf(p2), 2.f), 0.f);
            float r0 = p0 - f0, r1 = p1 - f1, r2 = p2 - f2;
            int i0 = (int)f0, i1 = (int)f1, i2 = (int)f2;
            float xs = xin[src * 32 + ch];
#pragma unroll
            for (int q = 0; q < 4; q++) {
                int bits = hi * 4 + q;
                int b0 = bits & 1, b1 = (bits >> 1) & 1, b2 = (bits >> 2) & 1;
                float bas = (b0 ? r0 : 1.f - r0) * (b1 ? r1 : 1.f - r1) * (b2 ? r2 : 1.f - r2);
                int idx = (i0 + b0) + 4 * (i1 + b1) + 16 * (i2 + b2);
                atomicAdd(&buf[((idx * 8 + t) << 5) + (ch ^ ((idx & 7) << 2))], bas * xs);
            }
        }
    }
    __syncthreads();
    // -------- phase B: einsum nkc,kcd -> nd --------
    int kk = lane >> 3, d8 = lane & 7;
    int k = wave * 8 + kk;
    const float* wk = wsp + k * 1024;
    float4 acc[8];
#pragma unroll
    for (int t = 0; t < 8; t++) acc[t] = make_float4(0.f, 0.f, 0.f, 0.f);
#pragma unroll
    for (int c4 = 0; c4 < 8; c4++) {
        float4 wv0 = *(const float4*)(wk + (c4 * 4 + 0) * 32 + d8 * 4);
        float4 wv1 = *(const float4*)(wk + (c4 * 4 + 1) * 32 + d8 * 4);
        float4 wv2 = *(const float4*)(wk + (c4 * 4 + 2) * 32 + d8 * 4);
        float4 wv3 = *(const float4*)(wk + (c4 * 4 + 3) * 32 + d8 * 4);
        int cp = (c4 ^ (k & 7)) << 2;
        const float* bp = &buf[(k * 8) << 5];
#pragma unroll
        for (int t = 0; t < 8; t++) {
            float4 bv = *(const float4*)(bp + (t << 5) + cp);
            acc[t].x += bv.x * wv0.x + bv.y * wv1.x + bv.z * wv2.x + bv.w * wv3.x;
            acc[t].y += bv.x * wv0.y + bv.y * wv1.y + bv.z * wv2.y + bv.w * wv3.y;
            acc[t].z += bv.x * wv0.z + bv.y * wv1.z + bv.z * wv2.z + bv.w * wv3.z;
            acc[t].w += bv.x * wv0.w + bv.y * wv1.w + bv.z * wv2.w + bv.w * wv3.w;
        }
    }
#pragma unroll
    for (int t = 0; t < 8; t++) {
        float sx = acc[t].x, sy = acc[t].y, sz = acc[t].z, sw = acc[t].w;
        sx += __shfl_xor(sx, 8);  sy += __shfl_xor(sy, 8);  sz += __shfl_xor(sz, 8);  sw += __shfl_xor(sw, 8);
        sx += __shfl_xor(sx, 16); sy += __shfl_xor(sy, 16); sz += __shfl_xor(sz, 16); sw += __shfl_xor(sw, 16);
        sx += __shfl_xor(sx, 32); sy += __shfl_xor(sy, 32); sz += __shfl_xor(sz, 32); sw += __shfl_xor(sw, 32);
        acc[t] = make_float4(sx, sy, sz, sw);
    }
    if (kk == 0) {
#pragma unroll
        for (int t = 0; t < 8; t++)
            *(float4*)&scr[wave * 256 + d8 * 32 + t * 4] = acc[t];
    }
    __syncthreads();
    if (tid < 256) {
        int t = tid >> 5, d = tid & 31;
        int n = nb + t;
        float v = 0.f;
#pragma unroll
        for (int ww = 0; ww < 8; ww++)
            v += scr[ww * 256 + (d >> 2) * 32 + t * 4 + (d & 3)];
        v /= degf[n];
        float rt = 0.f;
#pragma unroll
        for (int c = 0; c < 32; c++) rt += xt[t][c] * root[c * 32 + d];
        v += rt + bias[d];
        v = v >= 0.f ? v : 0.01f * v;   // LeakyReLU (both spline layers)
        out[n * 32 + d] = v;
        float s = v, s2 = v * v;
        s += __shfl_xor(s, 32); s2 += __shfl_xor(s2, 32);
        if (lane < 32) { atomicAdd(&scr2[d], s); atomicAdd(&scr2[32 + d], s2); }
    }
    __syncthreads();
    if (tid < 64) atomicAdd(&stats[tid], scr2[tid]);
}

// ---------------- K5: BN apply ----------------
__global__ void k_bn(const float* __restrict__ tin, const float* __restrict__ stats,
                     const float* __restrict__ gamma, const float* __restrict__ beta,
                     float* __restrict__ xout) {
    int i = blockIdx.x * 256 + threadIdx.x;   // grid exact
    int c = i & 31;
    float mu = stats[c] * (1.f / NN);
    float var = stats[32 + c] * (1.f / NN) - mu * mu;
    float g = gamma[c] * rsqrtf(var + 1e-5f);
    xout[i] = (tin[i] - mu) * g + beta[c];
}

// ---------------- K6a: NodeFormer pass 1 (k,v,phi_k -> kv,ksum,vbuf) ----------------
__global__ void __launch_bounds__(256) k_nf1(
        const float* __restrict__ x, const float* __restrict__ wqkv,
        const float* __restrict__ wp, const float* __restrict__ gumbel,
        float* __restrict__ vbuf, float* __restrict__ kvg) {
    __shared__ float kvloc[1280];             // [0..1023]=kv[h][m][dh], [1024..1279]=ksum[h][m]
    int tid = threadIdx.x;
    for (int i = tid; i < 1280; i += 256) kvloc[i] = 0.f;
    __syncthreads();
    int n = blockIdx.x * 256 + tid;
    int act = (n < NN) ? 1 : 0;
    int nc = act ? n : 0;
    int lane = tid & 63;
    float xr[32];
#pragma unroll
    for (int j4 = 0; j4 < 8; j4++) {
        float4 t4 = *(const float4*)&x[nc * 32 + j4 * 4];
        xr[j4*4+0] = t4.x; xr[j4*4+1] = t4.y; xr[j4*4+2] = t4.z; xr[j4*4+3] = t4.w;
    }
    float kr[32], vr[32];
#pragma unroll
    for (int j = 0; j < 32; j++) { kr[j] = 0.f; vr[j] = 0.f; }
#pragma unroll
    for (int c = 0; c < 32; c++) {
        float xc = xr[c];
        const float4* wk4 = (const float4*)(wqkv + 1024 + c * 32);
        const float4* wv4 = (const float4*)(wqkv + 2048 + c * 32);
#pragma unroll
        for (int j4 = 0; j4 < 8; j4++) {
            float4 a = wk4[j4], b = wv4[j4];
            kr[j4*4+0] += xc * a.x; kr[j4*4+1] += xc * a.y; kr[j4*4+2] += xc * a.z; kr[j4*4+3] += xc * a.w;
            vr[j4*4+0] += xc * b.x; vr[j4*4+1] += xc * b.y; vr[j4*4+2] += xc * b.z; vr[j4*4+3] += xc * b.w;
        }
    }
    if (act) {
#pragma unroll
        for (int j4 = 0; j4 < 8; j4++)
            *(float4*)&vbuf[n * 32 + j4 * 4] =
                make_float4(vr[j4*4], vr[j4*4+1], vr[j4*4+2], vr[j4*4+3]);
    }
    const float inv_rt2 = 0.70710678118f;     // 1/DH^0.25
    const float invSqM = 0.17677669529f;      // 1/sqrt(32)
#pragma unroll
    for (int h = 0; h < 8; h++) {
        float x0 = kr[h*4+0]*inv_rt2, x1 = kr[h*4+1]*inv_rt2;
        float x2 = kr[h*4+2]*inv_rt2, x3 = kr[h*4+3]*inv_rt2;
        float sq = 0.5f * (x0*x0 + x1*x1 + x2*x2 + x3*x3);
        float gs = __expf(gumbel[nc * 8 + h]) * invSqM * (float)act;  // tau=1
        const float* wph = wp + h * 128;
        float v0 = vr[h*4+0], v1 = vr[h*4+1], v2 = vr[h*4+2], v3 = vr[h*4+3];
        for (int mm = 0; mm < 32; mm++) {
            int m = (mm + lane) & 31;         // lane-stagger: avoid same-addr LDS atomics
            float pr = x0*wph[m] + x1*wph[32+m] + x2*wph[64+m] + x3*wph[96+m];
            float phk = __expf(pr - sq) * gs;
            atomicAdd(&kvloc[1024 + h*32 + m], phk);
            int b = (h * 32 + m) * 4;
            atomicAdd(&kvloc[b+0], phk * v0);
            atomicAdd(&kvloc[b+1], phk * v1);
            atomicAdd(&kvloc[b+2], phk * v2);
            atomicAdd(&kvloc[b+3], phk * v3);
        }
    }
    __syncthreads();
    for (int i = tid; i < 1280; i += 256) atomicAdd(&kvg[i], kvloc[i]);
}

// ---------------- K6b: NodeFormer pass 2 (phi_q, attn, rel, proj, BN-stats) ----------------
__global__ void __launch_bounds__(256) k_nf2(
        const float* __restrict__ x, const float* __restrict__ wqkv,
        const float* __restrict__ wp, const float* __restrict__ brel,
        const float* __restrict__ wo, const float* __restrict__ bo,
        const float* __restrict__ kvg, const int* __restrict__ rowptr,
        const float4* __restrict__ sedge, const float* __restrict__ degf,
        const float* __restrict__ vbuf, int do_leaky,
        float* __restrict__ out, float* __restrict__ stats) {
    int tid = threadIdx.x;
    int n = blockIdx.x * 256 + tid;
    int act = (n < NN) ? 1 : 0;
    int nc = act ? n : 0;
    float xr[32];
#pragma unroll
    for (int j4 = 0; j4 < 8; j4++) {
        float4 t4 = *(const float4*)&x[nc * 32 + j4 * 4];
        xr[j4*4+0] = t4.x; xr[j4*4+1] = t4.y; xr[j4*4+2] = t4.z; xr[j4*4+3] = t4.w;
    }
    float qr[32];
#pragma unroll
    for (int j = 0; j < 32; j++) qr[j] = 0.f;
#pragma unroll
    for (int c = 0; c < 32; c++) {
        float xc = xr[c];
        const float4* wq4 = (const float4*)(wqkv + c * 32);
#pragma unroll
        for (int j4 = 0; j4 < 8; j4++) {
            float4 a = wq4[j4];
            qr[j4*4+0] += xc * a.x; qr[j4*4+1] += xc * a.y;
            qr[j4*4+2] += xc * a.z; qr[j4*4+3] += xc * a.w;
        }
    }
    const float inv_rt2 = 0.70710678118f;
    const float invSqM = 0.17677669529f;
    float y[32];
#pragma unroll
    for (int h = 0; h < 8; h++) {
        float x0 = qr[h*4+0]*inv_rt2, x1 = qr[h*4+1]*inv_rt2;
        float x2 = qr[h*4+2]*inv_rt2, x3 = qr[h*4+3]*inv_rt2;
        float sq = 0.5f * (x0*x0 + x1*x1 + x2*x2 + x3*x3);
        const float* wph = wp + h * 128;
        const float* kvh = kvg + h * 128;
        const float* ksh = kvg + 1024 + h * 32;
        float den = 0.f, n0 = 0.f, n1 = 0.f, n2 = 0.f, n3 = 0.f;
        for (int m = 0; m < 32; m++) {
            float pr = x0*wph[m] + x1*wph[32+m] + x2*wph[64+m] + x3*wph[96+m];
            float phq = __expf(pr - sq) * invSqM;
            den += phq * ksh[m];
            n0 += phq * kvh[m*4+0];
            n1 += phq * kvh[m*4+1];
            n2 += phq * kvh[m*4+2];
            n3 += phq * kvh[m*4+3];
        }
        float inv = 1.f / (den + 1e-6f);
        y[h*4+0] = n0 * inv; y[h*4+1] = n1 * inv; y[h*4+2] = n2 * inv; y[h*4+3] = n3 * inv;
    }
    // relational bias term via CSR gather
    float rl[32];
#pragma unroll
    for (int j = 0; j < 32; j++) rl[j] = 0.f;
    int rs = rowptr[nc];
    int re = act ? rowptr[nc + 1] : rs;
    float dn = degf[nc];
    for (int e = rs; e < re; e++) {
        float4 ed = sedge[e];
        int src = __float_as_int(ed.x);
        float nrm = rsqrtf(degf[src] * dn);
#pragma unroll
        for (int j4 = 0; j4 < 8; j4++) {
            float4 vv = *(const float4*)&vbuf[src * 32 + j4 * 4];
            rl[j4*4+0] += nrm * vv.x; rl[j4*4+1] += nrm * vv.y;
            rl[j4*4+2] += nrm * vv.z; rl[j4*4+3] += nrm * vv.w;
        }
    }
#pragma unroll
    for (int h = 0; h < 8; h++) {
        float sg = 1.f / (1.f + __expf(-brel[h]));
        y[h*4+0] += sg * rl[h*4+0]; y[h*4+1] += sg * rl[h*4+1];
        y[h*4+2] += sg * rl[h*4+2]; y[h*4+3] += sg * rl[h*4+3];
    }
    float z[32];
#pragma unroll
    for (int d = 0; d < 32; d++) z[d] = bo[d];
#pragma unroll
    for (int j = 0; j < 32; j++) {
        float yv = y[j];
        const float4* wo4 = (const float4*)(wo + j * 32);
#pragma unroll
        for (int d4 = 0; d4 < 8; d4++) {
            float4 wv = wo4[d4];
            z[d4*4+0] += yv * wv.x; z[d4*4+1] += yv * wv.y;
            z[d4*4+2] += yv * wv.z; z[d4*4+3] += yv * wv.w;
        }
    }
    if (do_leaky) {
#pragma unroll
        for (int d = 0; d < 32; d++) z[d] = z[d] >= 0.f ? z[d] : 0.01f * z[d];
    }
    if (act) {
#pragma unroll
        for (int j4 = 0; j4 < 8; j4++)
            *(float4*)&out[n * 32 + j4 * 4] =
                make_float4(z[j4*4], z[j4*4+1], z[j4*4+2], z[j4*4+3]);
    }
    // BN stats: 64-lane butterfly per channel, lane0 atomics
#pragma unroll
    for (int d = 0; d < 32; d++) {
        float s = act ? z[d] : 0.f;
        float s2 = s * s;
        s += __shfl_xor(s, 1);  s2 += __shfl_xor(s2, 1);
        s += __shfl_xor(s, 2);  s2 += __shfl_xor(s2, 2);
        s += __shfl_xor(s, 4);  s2 += __shfl_xor(s2, 4);
        s += __shfl_xor(s, 8);  s2 += __shfl_xor(s2, 8);
        s += __shfl_xor(s, 16); s2 += __shfl_xor(s2, 16);
        s += __shfl_xor(s, 32); s2 += __shfl_xor(s2, 32);
        if ((tid & 63) == 0) { atomicAdd(&stats[d], s); atomicAdd(&stats[32 + d], s2); }
    }
}

extern "C" void kernel_launch(void* const* d_in, const int* in_sizes, int n_in,
                              void* d_out, int out_size, void* d_ws, size_t ws_size,
                              hipStream_t stream) {
    (void)in_sizes; (void)n_in; (void)out_size; (void)ws_size;
    const float* x_in  = (const float*)d_in[0];
    const int*   ei    = (const int*)d_in[1];
    const float* attr  = (const float*)d_in[2];
    const float* wsp1  = (const float*)d_in[3];
    const float* root1 = (const float*)d_in[4];
    const float* bias1 = (const float*)d_in[5];
    const float* wsp2  = (const float*)d_in[6];
    const float* root2 = (const float*)d_in[7];
    const float* bias2 = (const float*)d_in[8];
    const float* gam   = (const float*)d_in[9];
    const float* bet   = (const float*)d_in[10];
    const float* w1qkv = (const float*)d_in[11];
    const float* w1p   = (const float*)d_in[12];
    const float* b1rel = (const float*)d_in[13];
    const float* w1o   = (const float*)d_in[14];
    const float* b1o   = (const float*)d_in[15];
    const float* gum1  = (const float*)d_in[16];
    const float* w2qkv = (const float*)d_in[17];
    const float* w2p   = (const float*)d_in[18];
    const float* b2rel = (const float*)d_in[19];
    const float* w2o   = (const float*)d_in[20];
    const float* b2o   = (const float*)d_in[21];
    const float* gum2  = (const float*)d_in[22];
    float* outp = (float*)d_out;

    char* wsb = (char*)d_ws;
    size_t off = 0;
    auto carve = [&](size_t bytes) -> char* {
        char* p = wsb + off;
        off += (bytes + 255) & ~(size_t)255;
        return p;
    };
    int*    cnt    = (int*)carve((size_t)NN * 4);
    float*  kvg1   = (float*)carve(1280 * 4);
    float*  kvg2   = (float*)carve(1280 * 4);
    float*  stats  = (float*)carve(256 * 4);
    size_t zero_bytes = off;                     // everything above must start at 0
    int*    rowptr = (int*)carve((size_t)(NN + 1) * 4);
    int*    fill   = (int*)carve((size_t)NN * 4);
    float*  degf   = (float*)carve((size_t)NN * 4);
    float4* sedge  = (float4*)carve((size_t)NE * 16);
    float*  vbuf   = (float*)carve((size_t)NN * 32 * 4);
    float*  xa     = (float*)carve((size_t)NN * 32 * 4);
    float*  xb     = (float*)carve((size_t)NN * 32 * 4);
    float*  tb     = (float*)carve((size_t)NN * 32 * 4);

    hipMemsetAsync(d_ws, 0, zero_bytes, stream);
    k_hist<<<NE / 256, 256, 0, stream>>>(ei, cnt);
    k_scan<<<1, 1024, 0, stream>>>(cnt, rowptr, fill, degf);
    k_scatter<<<NE / 256, 256, 0, stream>>>(ei, attr, fill, sedge);

    // layer 1: spline + leaky + BN0
    k_spline<<<NN / 8, 512, 0, stream>>>(x_in, rowptr, sedge, degf, wsp1, root1, bias1, tb, stats);
    k_bn<<<NN * 32 / 256, 256, 0, stream>>>(tb, stats, gam, bet, xa);
    // layer 2: spline + leaky + BN1
    k_spline<<<NN / 8, 512, 0, stream>>>(xa, rowptr, sedge, degf, wsp2, root2, bias2, tb, stats + 64);
    k_bn<<<NN * 32 / 256, 256, 0, stream>>>(tb, stats + 64, gam + 32, bet + 32, xb);

    int nfgrid = (NN + 255) / 256;
    // layer 3: nodeformer1 + leaky + BN2
    k_nf1<<<nfgrid, 256, 0, stream>>>(xb, w1qkv, w1p, gum1, vbuf, kvg1);
    k_nf2<<<nfgrid, 256, 0, stream>>>(xb, w1qkv, w1p, b1rel, w1o, b1o, kvg1, rowptr, sedge,
                                      degf, vbuf, 1, tb, stats + 128);
    k_bn<<<NN * 32 / 256, 256, 0, stream>>>(tb, stats + 128, gam + 64, bet + 64, xa);
    // layer 4: nodeformer2 + BN3 (no leaky)
    k_nf1<<<nfgrid, 256, 0, stream>>>(xa, w2qkv, w2p, gum2, vbuf, kvg2);
    k_nf2<<<nfgrid, 256, 0, stream>>>(xa, w2qkv, w2p, b2rel, w2o, b2o, kvg2, rowptr, sedge,
                                      degf, vbuf, 0, tb, stats + 192);
    k_bn<<<NN * 32 / 256, 256, 0, stream>>>(tb, stats + 192, gam + 96, bet + 96, outp);
}

// Round 2
// 4500.779 us; speedup vs baseline: 1.0042x; 1.0042x over previous
//
#include <hip/hip_runtime.h>
#include <hip/hip_bf16.h>

#define NN 50000      // nodes
#define NE 800000     // edges
// C=32 channels, K=64 spline kernels, H=8 heads, DH=4, M=32 features

__device__ __forceinline__ void ldsAdd(float* p, float v) {
    __hip_atomic_fetch_add(p, v, __ATOMIC_RELAXED, __HIP_MEMORY_SCOPE_WORKGROUP);
}
__device__ __forceinline__ void gAdd(float* p, float v) {
    unsafeAtomicAdd(p, v);   // global_atomic_add_f32, no CAS loop
}

// ---------------- K1: histogram of dst ----------------
__global__ void k_hist(const int* __restrict__ ei, int* __restrict__ cnt) {
    int e = blockIdx.x * 256 + threadIdx.x;   // grid exact: 3125*256 = 800000
    atomicAdd(&cnt[ei[NE + e]], 1);
}

// ---------------- K2: exclusive scan (single block, shfl-based) ----------------
__global__ void __launch_bounds__(1024) k_scan(const int* __restrict__ cnt,
                                               int* __restrict__ rowptr,
                                               int* __restrict__ fill,
                                               float* __restrict__ degf) {
    __shared__ int wsum[16];
    int tid = threadIdx.x;
    int wave = tid >> 6, lane = tid & 63;
    int carry = 0;
    for (int base = 0; base < NN; base += 8192) {
        int i0 = base + tid * 8;
        int v[8], pre[8], s = 0;
#pragma unroll
        for (int j = 0; j < 8; j++) {
            int i = i0 + j;
            v[j] = (i < NN) ? cnt[i] : 0;
            pre[j] = s; s += v[j];
        }
        // inclusive wave scan of s
        int sc = s;
#pragma unroll
        for (int d = 1; d < 64; d <<= 1) {
            int t = __shfl_up(sc, d);
            if (lane >= d) sc += t;
        }
        if (lane == 63) wsum[wave] = sc;
        __syncthreads();
        int wpre = 0, total = 0;
#pragma unroll
        for (int w = 0; w < 16; w++) {
            int x = wsum[w];
            if (w < wave) wpre += x;
            total += x;
        }
        int excl = carry + wpre + (sc - s);
#pragma unroll
        for (int j = 0; j < 8; j++) {
            int i = i0 + j;
            if (i < NN) {
                int st = excl + pre[j];
                rowptr[i] = st;
                fill[i]   = st;
                degf[i]   = (float)(v[j] > 0 ? v[j] : 1);
                if (i == NN - 1) rowptr[NN] = st + v[j];
            }
        }
        carry += total;
        __syncthreads();   // protect wsum before next batch
    }
}

// ---------------- K3: scatter edges into CSR order ----------------
__global__ void k_scatter(const int* __restrict__ ei, const float* __restrict__ attr,
                          int* __restrict__ fill, float4* __restrict__ sedge,
                          int* __restrict__ sdst) {
    int e = blockIdx.x * 256 + threadIdx.x;
    int src = ei[e], dst = ei[NE + e];
    int pos = atomicAdd(&fill[dst], 1);
    float4 r;
    r.x = __int_as_float(src);
    r.y = attr[e * 3 + 0]; r.z = attr[e * 3 + 1]; r.w = attr[e * 3 + 2];
    sedge[pos] = r;
    sdst[pos] = dst;
}

// ---------------- K4: fused SplineConv + leaky + BN-stats ----------------
// 8 nodes/block, 512 threads. LDS buf layout: [k][t][c ^ ((k&7)<<2)]
__device__ __forceinline__ void edge_proc(float* __restrict__ buf, float4 ed, int t,
                                          float xs, int ch, int hi) {
    float p0 = ed.y * 3.f, p1 = ed.z * 3.f, p2 = ed.w * 3.f;
    float f0 = fmaxf(fminf(floorf(p0), 2.f), 0.f);
    float f1 = fmaxf(fminf(floorf(p1), 2.f), 0.f);
    float f2 = fmaxf(fminf(floorf(p2), 2.f), 0.f);
    float r0 = p0 - f0, r1 = p1 - f1, r2 = p2 - f2;
    int i0 = (int)f0, i1 = (int)f1, i2 = (int)f2;
#pragma unroll
    for (int q = 0; q < 4; q++) {
        int bits = hi * 4 + q;
        int b0 = bits & 1, b1 = (bits >> 1) & 1, b2 = (bits >> 2) & 1;
        float bas = (b0 ? r0 : 1.f - r0) * (b1 ? r1 : 1.f - r1) * (b2 ? r2 : 1.f - r2);
        int idx = (i0 + b0) + 4 * (i1 + b1) + 16 * (i2 + b2);
        ldsAdd(&buf[((idx * 8 + t) << 5) + (ch ^ ((idx & 7) << 2))], bas * xs);
    }
}

__global__ void __launch_bounds__(512) k_spline(
        const float* __restrict__ xin, const int* __restrict__ rowptr,
        const float4* __restrict__ sedge, const int* __restrict__ sdst,
        const float* __restrict__ degf,
        const float* __restrict__ wsp, const float* __restrict__ root,
        const float* __restrict__ bias, float* __restrict__ out,
        float* __restrict__ stats) {
    __shared__ __align__(16) float buf[16384];  // 64k * 8t * 32c
    __shared__ __align__(16) float xt[8][32];
    __shared__ __align__(16) float scr[2048];
    __shared__ float scr2[64];
    int tid = threadIdx.x;
    int wave = tid >> 6, lane = tid & 63;
    for (int i = tid; i < 16384; i += 512) buf[i] = 0.f;
    if (tid < 64) scr2[tid] = 0.f;
    int nb = blockIdx.x * 8;                    // NN % 8 == 0, always in-bounds
    if (tid < 256) {
        int t = tid >> 5, c = tid & 31;
        xt[t][c] = xin[(nb + t) * 32 + c];
    }
    __syncthreads();
    // -------- phase A: block's edges split evenly across 8 waves, 4-batched --------
    {
        int bs = rowptr[nb], be = rowptr[nb + 8];
        int tot = be - bs;
        int chunk = (tot + 7) >> 3;
        int ws_ = bs + wave * chunk;
        int we_ = ws_ + chunk; if (we_ > be) we_ = be;
        int ch = lane & 31, hi = lane >> 5;
        int e0 = ws_;
        for (; e0 + 4 <= we_; e0 += 4) {
            float4 ed0 = sedge[e0 + 0];
            float4 ed1 = sedge[e0 + 1];
            float4 ed2 = sedge[e0 + 2];
            float4 ed3 = sedge[e0 + 3];
            int t0 = sdst[e0 + 0] - nb;
            int t1 = sdst[e0 + 1] - nb;
            int t2 = sdst[e0 + 2] - nb;
            int t3 = sdst[e0 + 3] - nb;
            float xs0 = xin[__float_as_int(ed0.x) * 32 + ch];
            float xs1 = xin[__float_as_int(ed1.x) * 32 + ch];
            float xs2 = xin[__float_as_int(ed2.x) * 32 + ch];
            float xs3 = xin[__float_as_int(ed3.x) * 32 + ch];
            edge_proc(buf, ed0, t0, xs0, ch, hi);
            edge_proc(buf, ed1, t1, xs1, ch, hi);
            edge_proc(buf, ed2, t2, xs2, ch, hi);
            edge_proc(buf, ed3, t3, xs3, ch, hi);
        }
        for (; e0 < we_; e0++) {
            float4 ed = sedge[e0];
            int t = sdst[e0] - nb;
            float xs = xin[__float_as_int(ed.x) * 32 + ch];
            edge_proc(buf, ed, t, xs, ch, hi);
        }
    }
    __syncthreads();
    // -------- phase B: einsum nkc,kcd -> nd --------
    int kk = lane >> 3, d8 = lane & 7;
    int k = wave * 8 + kk;
    const float* wk = wsp + k * 1024;
    float4 acc[8];
#pragma unroll
    for (int t = 0; t < 8; t++) acc[t] = make_float4(0.f, 0.f, 0.f, 0.f);
#pragma unroll
    for (int c4 = 0; c4 < 8; c4++) {
        float4 wv0 = *(const float4*)(wk + (c4 * 4 + 0) * 32 + d8 * 4);
        float4 wv1 = *(const float4*)(wk + (c4 * 4 + 1) * 32 + d8 * 4);
        float4 wv2 = *(const float4*)(wk + (c4 * 4 + 2) * 32 + d8 * 4);
        float4 wv3 = *(const float4*)(wk + (c4 * 4 + 3) * 32 + d8 * 4);
        int cp = (c4 ^ (k & 7)) << 2;
        const float* bp = &buf[(k * 8) << 5];
#pragma unroll
        for (int t = 0; t < 8; t++) {
            float4 bv = *(const float4*)(bp + (t << 5) + cp);
            acc[t].x += bv.x * wv0.x + bv.y * wv1.x + bv.z * wv2.x + bv.w * wv3.x;
            acc[t].y += bv.x * wv0.y + bv.y * wv1.y + bv.z * wv2.y + bv.w * wv3.y;
            acc[t].z += bv.x * wv0.z + bv.y * wv1.z + bv.z * wv2.z + bv.w * wv3.z;
            acc[t].w += bv.x * wv0.w + bv.y * wv1.w + bv.z * wv2.w + bv.w * wv3.w;
        }
    }
#pragma unroll
    for (int t = 0; t < 8; t++) {
        float sx = acc[t].x, sy = acc[t].y, sz = acc[t].z, sw = acc[t].w;
        sx += __shfl_xor(sx, 8);  sy += __shfl_xor(sy, 8);  sz += __shfl_xor(sz, 8);  sw += __shfl_xor(sw, 8);
        sx += __shfl_xor(sx, 16); sy += __shfl_xor(sy, 16); sz += __shfl_xor(sz, 16); sw += __shfl_xor(sw, 16);
        sx += __shfl_xor(sx, 32); sy += __shfl_xor(sy, 32); sz += __shfl_xor(sz, 32); sw += __shfl_xor(sw, 32);
        acc[t] = make_float4(sx, sy, sz, sw);
    }
    if (kk == 0) {
#pragma unroll
        for (int t = 0; t < 8; t++)
            *(float4*)&scr[wave * 256 + d8 * 32 + t * 4] = acc[t];
    }
    __syncthreads();
    if (tid < 256) {
        int t = tid >> 5, d = tid & 31;
        int n = nb + t;
        float v = 0.f;
#pragma unroll
        for (int ww = 0; ww < 8; ww++)
            v += scr[ww * 256 + (d >> 2) * 32 + t * 4 + (d & 3)];
        v /= degf[n];
        float rt = 0.f;
#pragma unroll
        for (int c = 0; c < 32; c++) rt += xt[t][c] * root[c * 32 + d];
        v += rt + bias[d];
        v = v >= 0.f ? v : 0.01f * v;   // LeakyReLU (both spline layers)
        out[n * 32 + d] = v;
        float s = v, s2 = v * v;
        s += __shfl_xor(s, 32); s2 += __shfl_xor(s2, 32);
        if (lane < 32) { ldsAdd(&scr2[d], s); ldsAdd(&scr2[32 + d], s2); }
    }
    __syncthreads();
    if (tid < 64) gAdd(&stats[tid], scr2[tid]);
}

// ---------------- K5: BN apply ----------------
__global__ void k_bn(const float* __restrict__ tin, const float* __restrict__ stats,
                     const float* __restrict__ gamma, const float* __restrict__ beta,
                     float* __restrict__ xout) {
    int i = blockIdx.x * 256 + threadIdx.x;   // grid exact
    int c = i & 31;
    float mu = stats[c] * (1.f / NN);
    float var = stats[32 + c] * (1.f / NN) - mu * mu;
    float g = gamma[c] * rsqrtf(var + 1e-5f);
    xout[i] = (tin[i] - mu) * g + beta[c];
}

// ---------------- K6a: NodeFormer pass 1 (k,v,phi_k -> kv,ksum,vbuf) ----------------
__global__ void __launch_bounds__(256) k_nf1(
        const float* __restrict__ x, const float* __restrict__ wqkv,
        const float* __restrict__ wp, const float* __restrict__ gumbel,
        float* __restrict__ vbuf, float* __restrict__ kvg) {
    __shared__ float kvloc[1280];             // [0..1023]=kv[h][m][dh], [1024..1279]=ksum[h][m]
    int tid = threadIdx.x;
    for (int i = tid; i < 1280; i += 256) kvloc[i] = 0.f;
    __syncthreads();
    int n = blockIdx.x * 256 + tid;
    int act = (n < NN) ? 1 : 0;
    int nc = act ? n : 0;
    int lane = tid & 63;
    float xr[32];
#pragma unroll
    for (int j4 = 0; j4 < 8; j4++) {
        float4 t4 = *(const float4*)&x[nc * 32 + j4 * 4];
        xr[j4*4+0] = t4.x; xr[j4*4+1] = t4.y; xr[j4*4+2] = t4.z; xr[j4*4+3] = t4.w;
    }
    float kr[32], vr[32];
#pragma unroll
    for (int j = 0; j < 32; j++) { kr[j] = 0.f; vr[j] = 0.f; }
#pragma unroll
    for (int c = 0; c < 32; c++) {
        float xc = xr[c];
        const float4* wk4 = (const float4*)(wqkv + 1024 + c * 32);
        const float4* wv4 = (const float4*)(wqkv + 2048 + c * 32);
#pragma unroll
        for (int j4 = 0; j4 < 8; j4++) {
            float4 a = wk4[j4], b = wv4[j4];
            kr[j4*4+0] += xc * a.x; kr[j4*4+1] += xc * a.y; kr[j4*4+2] += xc * a.z; kr[j4*4+3] += xc * a.w;
            vr[j4*4+0] += xc * b.x; vr[j4*4+1] += xc * b.y; vr[j4*4+2] += xc * b.z; vr[j4*4+3] += xc * b.w;
        }
    }
    if (act) {
#pragma unroll
        for (int j4 = 0; j4 < 8; j4++)
            *(float4*)&vbuf[n * 32 + j4 * 4] =
                make_float4(vr[j4*4], vr[j4*4+1], vr[j4*4+2], vr[j4*4+3]);
    }
    const float inv_rt2 = 0.70710678118f;     // 1/DH^0.25
    const float invSqM = 0.17677669529f;      // 1/sqrt(32)
#pragma unroll
    for (int h = 0; h < 8; h++) {
        float x0 = kr[h*4+0]*inv_rt2, x1 = kr[h*4+1]*inv_rt2;
        float x2 = kr[h*4+2]*inv_rt2, x3 = kr[h*4+3]*inv_rt2;
        float sq = 0.5f * (x0*x0 + x1*x1 + x2*x2 + x3*x3);
        float gs = __expf(gumbel[nc * 8 + h]) * invSqM * (float)act;  // tau=1
        const float* wph = wp + h * 128;
        float v0 = vr[h*4+0], v1 = vr[h*4+1], v2 = vr[h*4+2], v3 = vr[h*4+3];
        for (int mm = 0; mm < 32; mm++) {
            int m = (mm + lane) & 31;         // lane-stagger: avoid same-addr LDS atomics
            float pr = x0*wph[m] + x1*wph[32+m] + x2*wph[64+m] + x3*wph[96+m];
            float phk = __expf(pr - sq) * gs;
            ldsAdd(&kvloc[1024 + h*32 + m], phk);
            int b = (h * 32 + m) * 4;
            ldsAdd(&kvloc[b+0], phk * v0);
            ldsAdd(&kvloc[b+1], phk * v1);
            ldsAdd(&kvloc[b+2], phk * v2);
            ldsAdd(&kvloc[b+3], phk * v3);
        }
    }
    __syncthreads();
    for (int i = tid; i < 1280; i += 256) gAdd(&kvg[i], kvloc[i]);
}

// ---------------- K6b: NodeFormer pass 2 (phi_q, attn, rel, proj, BN-stats) ----------------
__global__ void __launch_bounds__(256) k_nf2(
        const float* __restrict__ x, const float* __restrict__ wqkv,
        const float* __restrict__ wp, const float* __restrict__ brel,
        const float* __restrict__ wo, const float* __restrict__ bo,
        const float* __restrict__ kvg, const int* __restrict__ rowptr,
        const float4* __restrict__ sedge, const float* __restrict__ degf,
        const float* __restrict__ vbuf, int do_leaky,
        float* __restrict__ out, float* __restrict__ stats) {
    int tid = threadIdx.x;
    int n = blockIdx.x * 256 + tid;
    int act = (n < NN) ? 1 : 0;
    int nc = act ? n : 0;
    float xr[32];
#pragma unroll
    for (int j4 = 0; j4 < 8; j4++) {
        float4 t4 = *(const float4*)&x[nc * 32 + j4 * 4];
        xr[j4*4+0] = t4.x; xr[j4*4+1] = t4.y; xr[j4*4+2] = t4.z; xr[j4*4+3] = t4.w;
    }
    float qr[32];
#pragma unroll
    for (int j = 0; j < 32; j++) qr[j] = 0.f;
#pragma unroll
    for (int c = 0; c < 32; c++) {
        float xc = xr[c];
        const float4* wq4 = (const float4*)(wqkv + c * 32);
#pragma unroll
        for (int j4 = 0; j4 < 8; j4++) {
            float4 a = wq4[j4];
            qr[j4*4+0] += xc * a.x; qr[j4*4+1] += xc * a.y;
            qr[j4*4+2] += xc * a.z; qr[j4*4+3] += xc * a.w;
        }
    }
    const float inv_rt2 = 0.70710678118f;
    const float invSqM = 0.17677669529f;
    float y[32];
#pragma unroll
    for (int h = 0; h < 8; h++) {
        float x0 = qr[h*4+0]*inv_rt2, x1 = qr[h*4+1]*inv_rt2;
        float x2 = qr[h*4+2]*inv_rt2, x3 = qr[h*4+3]*inv_rt2;
        float sq = 0.5f * (x0*x0 + x1*x1 + x2*x2 + x3*x3);
        const float* wph = wp + h * 128;
        const float* kvh = kvg + h * 128;
        const float* ksh = kvg + 1024 + h * 32;
        float den = 0.f, n0 = 0.f, n1 = 0.f, n2 = 0.f, n3 = 0.f;
        for (int m = 0; m < 32; m++) {
            float pr = x0*wph[m] + x1*wph[32+m] + x2*wph[64+m] + x3*wph[96+m];
            float phq = __expf(pr - sq) * invSqM;
            den += phq * ksh[m];
            n0 += phq * kvh[m*4+0];
            n1 += phq * kvh[m*4+1];
            n2 += phq * kvh[m*4+2];
            n3 += phq * kvh[m*4+3];
        }
        float inv = 1.f / (den + 1e-6f);
        y[h*4+0] = n0 * inv; y[h*4+1] = n1 * inv; y[h*4+2] = n2 * inv; y[h*4+3] = n3 * inv;
    }
    // relational bias term via CSR gather (2-batched to overlap latency)
    float rl[32];
#pragma unroll
    for (int j = 0; j < 32; j++) rl[j] = 0.f;
    int rs = rowptr[nc];
    int re = act ? rowptr[nc + 1] : rs;
    float dn = degf[nc];
    int e = rs;
    for (; e + 2 <= re; e += 2) {
        float4 ed0 = sedge[e], ed1 = sedge[e + 1];
        int s0 = __float_as_int(ed0.x), s1 = __float_as_int(ed1.x);
        float nr0 = rsqrtf(degf[s0] * dn);
        float nr1 = rsqrtf(degf[s1] * dn);
#pragma unroll
        for (int j4 = 0; j4 < 8; j4++) {
            float4 v0 = *(const float4*)&vbuf[s0 * 32 + j4 * 4];
            float4 v1 = *(const float4*)&vbuf[s1 * 32 + j4 * 4];
            rl[j4*4+0] += nr0 * v0.x + nr1 * v1.x;
            rl[j4*4+1] += nr0 * v0.y + nr1 * v1.y;
            rl[j4*4+2] += nr0 * v0.z + nr1 * v1.z;
            rl[j4*4+3] += nr0 * v0.w + nr1 * v1.w;
        }
    }
    for (; e < re; e++) {
        float4 ed = sedge[e];
        int src = __float_as_int(ed.x);
        float nrm = rsqrtf(degf[src] * dn);
#pragma unroll
        for (int j4 = 0; j4 < 8; j4++) {
            float4 vv = *(const float4*)&vbuf[src * 32 + j4 * 4];
            rl[j4*4+0] += nrm * vv.x; rl[j4*4+1] += nrm * vv.y;
            rl[j4*4+2] += nrm * vv.z; rl[j4*4+3] += nrm * vv.w;
        }
    }
#pragma unroll
    for (int h = 0; h < 8; h++) {
        float sg = 1.f / (1.f + __expf(-brel[h]));
        y[h*4+0] += sg * rl[h*4+0]; y[h*4+1] += sg * rl[h*4+1];
        y[h*4+2] += sg * rl[h*4+2]; y[h*4+3] += sg * rl[h*4+3];
    }
    float z[32];
#pragma unroll
    for (int d = 0; d < 32; d++) z[d] = bo[d];
#pragma unroll
    for (int j = 0; j < 32; j++) {
        float yv = y[j];
        const float4* wo4 = (const float4*)(wo + j * 32);
#pragma unroll
        for (int d4 = 0; d4 < 8; d4++) {
            float4 wv = wo4[d4];
            z[d4*4+0] += yv * wv.x; z[d4*4+1] += yv * wv.y;
            z[d4*4+2] += yv * wv.z; z[d4*4+3] += yv * wv.w;
        }
    }
    if (do_leaky) {
#pragma unroll
        for (int d = 0; d < 32; d++) z[d] = z[d] >= 0.f ? z[d] : 0.01f * z[d];
    }
    if (act) {
#pragma unroll
        for (int j4 = 0; j4 < 8; j4++)
            *(float4*)&out[n * 32 + j4 * 4] =
                make_float4(z[j4*4], z[j4*4+1], z[j4*4+2], z[j4*4+3]);
    }
    // BN stats: 64-lane butterfly per channel, lane0 atomics
#pragma unroll
    for (int d = 0; d < 32; d++) {
        float s = act ? z[d] : 0.f;
        float s2 = s * s;
        s += __shfl_xor(s, 1);  s2 += __shfl_xor(s2, 1);
        s += __shfl_xor(s, 2);  s2 += __shfl_xor(s2, 2);
        s += __shfl_xor(s, 4);  s2 += __shfl_xor(s2, 4);
        s += __shfl_xor(s, 8);  s2 += __shfl_xor(s2, 8);
        s += __shfl_xor(s, 16); s2 += __shfl_xor(s2, 16);
        s += __shfl_xor(s, 32); s2 += __shfl_xor(s2, 32);
        if ((tid & 63) == 0) { gAdd(&stats[d], s); gAdd(&stats[32 + d], s2); }
    }
}

extern "C" void kernel_launch(void* const* d_in, const int* in_sizes, int n_in,
                              void* d_out, int out_size, void* d_ws, size_t ws_size,
                              hipStream_t stream) {
    (void)in_sizes; (void)n_in; (void)out_size; (void)ws_size;
    const float* x_in  = (const float*)d_in[0];
    const int*   ei    = (const int*)d_in[1];
    const float* attr  = (const float*)d_in[2];
    const float* wsp1  = (const float*)d_in[3];
    const float* root1 = (const float*)d_in[4];
    const float* bias1 = (const float*)d_in[5];
    const float* wsp2  = (const float*)d_in[6];
    const float* root2 = (const float*)d_in[7];
    const float* bias2 = (const float*)d_in[8];
    const float* gam   = (const float*)d_in[9];
    const float* bet   = (const float*)d_in[10];
    const float* w1qkv = (const float*)d_in[11];
    const float* w1p   = (const float*)d_in[12];
    const float* b1rel = (const float*)d_in[13];
    const float* w1o   = (const float*)d_in[14];
    const float* b1o   = (const float*)d_in[15];
    const float* gum1  = (const float*)d_in[16];
    const float* w2qkv = (const float*)d_in[17];
    const float* w2p   = (const float*)d_in[18];
    const float* b2rel = (const float*)d_in[19];
    const float* w2o   = (const float*)d_in[20];
    const float* b2o   = (const float*)d_in[21];
    const float* gum2  = (const float*)d_in[22];
    float* outp = (float*)d_out;

    char* wsb = (char*)d_ws;
    size_t off = 0;
    auto carve = [&](size_t bytes) -> char* {
        char* p = wsb + off;
        off += (bytes + 255) & ~(size_t)255;
        return p;
    };
    int*    cnt    = (int*)carve((size_t)NN * 4);
    float*  kvg1   = (float*)carve(1280 * 4);
    float*  kvg2   = (float*)carve(1280 * 4);
    float*  stats  = (float*)carve(256 * 4);
    size_t zero_bytes = off;                     // everything above must start at 0
    int*    rowptr = (int*)carve((size_t)(NN + 1) * 4);
    int*    fill   = (int*)carve((size_t)NN * 4);
    float*  degf   = (float*)carve((size_t)NN * 4);
    float4* sedge  = (float4*)carve((size_t)NE * 16);
    int*    sdst   = (int*)carve((size_t)NE * 4);
    float*  vbuf   = (float*)carve((size_t)NN * 32 * 4);
    float*  xa     = (float*)carve((size_t)NN * 32 * 4);
    float*  xb     = (float*)carve((size_t)NN * 32 * 4);
    float*  tb     = (float*)carve((size_t)NN * 32 * 4);

    hipMemsetAsync(d_ws, 0, zero_bytes, stream);
    k_hist<<<NE / 256, 256, 0, stream>>>(ei, cnt);
    k_scan<<<1, 1024, 0, stream>>>(cnt, rowptr, fill, degf);
    k_scatter<<<NE / 256, 256, 0, stream>>>(ei, attr, fill, sedge, sdst);

    // layer 1: spline + leaky + BN0
    k_spline<<<NN / 8, 512, 0, stream>>>(x_in, rowptr, sedge, sdst, degf, wsp1, root1, bias1, tb, stats);
    k_bn<<<NN * 32 / 256, 256, 0, stream>>>(tb, stats, gam, bet, xa);
    // layer 2: spline + leaky + BN1
    k_spline<<<NN / 8, 512, 0, stream>>>(xa, rowptr, sedge, sdst, degf, wsp2, root2, bias2, tb, stats + 64);
    k_bn<<<NN * 32 / 256, 256, 0, stream>>>(tb, stats + 64, gam + 32, bet + 32, xb);

    int nfgrid = (NN + 255) / 256;
    // layer 3: nodeformer1 + leaky + BN2
    k_nf1<<<nfgrid, 256, 0, stream>>>(xb, w1qkv, w1p, gum1, vbuf, kvg1);
    k_nf2<<<nfgrid, 256, 0, stream>>>(xb, w1qkv, w1p, b1rel, w1o, b1o, kvg1, rowptr, sedge,
                                      degf, vbuf, 1, tb, stats + 128);
    k_bn<<<NN * 32 / 256, 256, 0, stream>>>(tb, stats + 128, gam + 64, bet + 64, xa);
    // layer 4: nodeformer2 + BN3 (no leaky)
    k_nf1<<<nfgrid, 256, 0, stream>>>(xa, w2qkv, w2p, gum2, vbuf, kvg2);
    k_nf2<<<nfgrid, 256, 0, stream>>>(xa, w2qkv, w2p, b2rel, w2o, b2o, kvg2, rowptr, sedge,
                                      degf, vbuf, 0, tb, stats + 192);
    k_bn<<<NN * 32 / 256, 256, 0, stream>>>(tb, stats + 192, gam + 96, bet + 96, outp);
}

// Round 3
// 3833.035 us; speedup vs baseline: 1.1791x; 1.1742x over previous
//
#include <hip/hip_runtime.h>
#include <hip/hip_bf16.h>

#define NN 50000      // nodes
#define NE 800000     // edges
// C=32 channels, K=64 spline kernels, H=8 heads, DH=4, M=32 features

__device__ __forceinline__ void ldsAdd(float* p, float v) {
    __hip_atomic_fetch_add(p, v, __ATOMIC_RELAXED, __HIP_MEMORY_SCOPE_WORKGROUP);
}
__device__ __forceinline__ void gAdd(float* p, float v) {
    unsafeAtomicAdd(p, v);   // global_atomic_add_f32, no CAS loop
}

// ---------------- K1: histogram of dst ----------------
__global__ void k_hist(const int* __restrict__ ei, int* __restrict__ cnt) {
    int e = blockIdx.x * 256 + threadIdx.x;   // grid exact: 3125*256 = 800000
    atomicAdd(&cnt[ei[NE + e]], 1);
}

// ---------------- K2: exclusive scan (single block, shfl-based) ----------------
__global__ void __launch_bounds__(1024) k_scan(const int* __restrict__ cnt,
                                               int* __restrict__ rowptr,
                                               int* __restrict__ fill,
                                               float* __restrict__ degf) {
    __shared__ int wsum[16];
    int tid = threadIdx.x;
    int wave = tid >> 6, lane = tid & 63;
    int carry = 0;
    for (int base = 0; base < NN; base += 8192) {
        int i0 = base + tid * 8;
        int v[8], pre[8], s = 0;
#pragma unroll
        for (int j = 0; j < 8; j++) {
            int i = i0 + j;
            v[j] = (i < NN) ? cnt[i] : 0;
            pre[j] = s; s += v[j];
        }
        int sc = s;
#pragma unroll
        for (int d = 1; d < 64; d <<= 1) {
            int t = __shfl_up(sc, d);
            if (lane >= d) sc += t;
        }
        if (lane == 63) wsum[wave] = sc;
        __syncthreads();
        int wpre = 0, total = 0;
#pragma unroll
        for (int w = 0; w < 16; w++) {
            int x = wsum[w];
            if (w < wave) wpre += x;
            total += x;
        }
        int excl = carry + wpre + (sc - s);
#pragma unroll
        for (int j = 0; j < 8; j++) {
            int i = i0 + j;
            if (i < NN) {
                int st = excl + pre[j];
                rowptr[i] = st;
                fill[i]   = st;
                degf[i]   = (float)(v[j] > 0 ? v[j] : 1);
                if (i == NN - 1) rowptr[NN] = st + v[j];
            }
        }
        carry += total;
        __syncthreads();
    }
}

// ---------------- K3: scatter edges into CSR order ----------------
__global__ void k_scatter(const int* __restrict__ ei, const float* __restrict__ attr,
                          int* __restrict__ fill, float4* __restrict__ sedge) {
    int e = blockIdx.x * 256 + threadIdx.x;
    int src = ei[e], dst = ei[NE + e];
    int pos = atomicAdd(&fill[dst], 1);
    float4 r;
    r.x = __int_as_float(src);
    r.y = attr[e * 3 + 0]; r.z = attr[e * 3 + 1]; r.w = attr[e * 3 + 2];
    sedge[pos] = r;
}

// ---------------- K4: fused SplineConv + leaky + BN-stats ----------------
// 4 nodes/block, 256 threads. LDS buf layout: [idx(64)][t(4)][c ^ ((idx&7)<<2)]
__device__ __forceinline__ void edge_proc(float* __restrict__ buf, float4 ed, int t,
                                          float xs, int ch, int hi) {
    float p0 = ed.y * 3.f, p1 = ed.z * 3.f, p2 = ed.w * 3.f;
    float f0 = fmaxf(fminf(floorf(p0), 2.f), 0.f);
    float f1 = fmaxf(fminf(floorf(p1), 2.f), 0.f);
    float f2 = fmaxf(fminf(floorf(p2), 2.f), 0.f);
    float r0 = p0 - f0, r1 = p1 - f1, r2 = p2 - f2;
    int i0 = (int)f0, i1 = (int)f1, i2 = (int)f2;
#pragma unroll
    for (int q = 0; q < 4; q++) {
        int bits = hi * 4 + q;
        int b0 = bits & 1, b1 = (bits >> 1) & 1, b2 = (bits >> 2) & 1;
        float bas = (b0 ? r0 : 1.f - r0) * (b1 ? r1 : 1.f - r1) * (b2 ? r2 : 1.f - r2);
        int idx = (i0 + b0) + 4 * (i1 + b1) + 16 * (i2 + b2);
        ldsAdd(&buf[((idx * 4 + t) << 5) + (ch ^ ((idx & 7) << 2))], bas * xs);
    }
}

__global__ void __launch_bounds__(256) k_spline(
        const float* __restrict__ xin, const int* __restrict__ rowptr,
        const float4* __restrict__ sedge, const float* __restrict__ degf,
        const float* __restrict__ wsp, const float* __restrict__ root,
        const float* __restrict__ bias, float* __restrict__ out,
        float* __restrict__ stats) {
    __shared__ __align__(16) float buf[8192];   // 64k * 4t * 32c = 32 KB
    __shared__ __align__(16) float xt[4][32];
    __shared__ __align__(16) float scr[1024];   // [wh(8)][d8(8)][t(4)][4]
    __shared__ float scr2[64];
    int tid = threadIdx.x;
    int wave = tid >> 6, lane = tid & 63;
    for (int i = tid; i < 8192; i += 256) buf[i] = 0.f;
    if (tid < 64) scr2[tid] = 0.f;
    int nb = blockIdx.x * 4;                    // NN % 4 == 0
    if (tid < 128) {
        int t = tid >> 5, c = tid & 31;
        xt[t][c] = xin[(nb + t) * 32 + c];
    }
    __syncthreads();
    // -------- phase A: wave w owns node nb+w, 4-batched edge loop --------
    {
        int n = nb + wave;
        int rs = rowptr[n], re = rowptr[n + 1];
        int ch = lane & 31, hi = lane >> 5;
        int e = rs;
        for (; e + 4 <= re; e += 4) {
            float4 e0 = sedge[e + 0];
            float4 e1 = sedge[e + 1];
            float4 e2 = sedge[e + 2];
            float4 e3 = sedge[e + 3];
            float xs0 = xin[__float_as_int(e0.x) * 32 + ch];
            float xs1 = xin[__float_as_int(e1.x) * 32 + ch];
            float xs2 = xin[__float_as_int(e2.x) * 32 + ch];
            float xs3 = xin[__float_as_int(e3.x) * 32 + ch];
            edge_proc(buf, e0, wave, xs0, ch, hi);
            edge_proc(buf, e1, wave, xs1, ch, hi);
            edge_proc(buf, e2, wave, xs2, ch, hi);
            edge_proc(buf, e3, wave, xs3, ch, hi);
        }
        for (; e < re; e++) {
            float4 ed = sedge[e];
            float xs = xin[__float_as_int(ed.x) * 32 + ch];
            edge_proc(buf, ed, wave, xs, ch, hi);
        }
    }
    __syncthreads();
    // -------- phase B: einsum nkc,kcd -> nd ; k = half*32 + wave*8 + kk --------
    int kk = lane >> 3, d8 = lane & 7;
    float4 acc[2][4];
#pragma unroll
    for (int hf = 0; hf < 2; hf++)
#pragma unroll
        for (int t = 0; t < 4; t++) acc[hf][t] = make_float4(0.f, 0.f, 0.f, 0.f);
#pragma unroll
    for (int hf = 0; hf < 2; hf++) {
        int k = hf * 32 + wave * 8 + kk;
        const float* wk = wsp + k * 1024;
#pragma unroll
        for (int c4 = 0; c4 < 8; c4++) {
            float4 wv0 = *(const float4*)(wk + (c4 * 4 + 0) * 32 + d8 * 4);
            float4 wv1 = *(const float4*)(wk + (c4 * 4 + 1) * 32 + d8 * 4);
            float4 wv2 = *(const float4*)(wk + (c4 * 4 + 2) * 32 + d8 * 4);
            float4 wv3 = *(const float4*)(wk + (c4 * 4 + 3) * 32 + d8 * 4);
            int cp = (c4 ^ (k & 7)) << 2;
            const float* bp = &buf[(k * 4) << 5];
#pragma unroll
            for (int t = 0; t < 4; t++) {
                float4 bv = *(const float4*)(bp + (t << 5) + cp);
                acc[hf][t].x += bv.x * wv0.x + bv.y * wv1.x + bv.z * wv2.x + bv.w * wv3.x;
                acc[hf][t].y += bv.x * wv0.y + bv.y * wv1.y + bv.z * wv2.y + bv.w * wv3.y;
                acc[hf][t].z += bv.x * wv0.z + bv.y * wv1.z + bv.z * wv2.z + bv.w * wv3.z;
                acc[hf][t].w += bv.x * wv0.w + bv.y * wv1.w + bv.z * wv2.w + bv.w * wv3.w;
            }
        }
    }
#pragma unroll
    for (int hf = 0; hf < 2; hf++)
#pragma unroll
    for (int t = 0; t < 4; t++) {
        float sx = acc[hf][t].x, sy = acc[hf][t].y, sz = acc[hf][t].z, sw = acc[hf][t].w;
        sx += __shfl_xor(sx, 8);  sy += __shfl_xor(sy, 8);  sz += __shfl_xor(sz, 8);  sw += __shfl_xor(sw, 8);
        sx += __shfl_xor(sx, 16); sy += __shfl_xor(sy, 16); sz += __shfl_xor(sz, 16); sw += __shfl_xor(sw, 16);
        sx += __shfl_xor(sx, 32); sy += __shfl_xor(sy, 32); sz += __shfl_xor(sz, 32); sw += __shfl_xor(sw, 32);
        acc[hf][t] = make_float4(sx, sy, sz, sw);
    }
    if (kk == 0) {
#pragma unroll
        for (int hf = 0; hf < 2; hf++)
#pragma unroll
        for (int t = 0; t < 4; t++)
            *(float4*)&scr[(wave * 2 + hf) * 128 + d8 * 16 + t * 4] = acc[hf][t];
    }
    __syncthreads();
    if (tid < 128) {
        int t = tid >> 5, d = tid & 31;
        int n = nb + t;
        float v = 0.f;
#pragma unroll
        for (int wh = 0; wh < 8; wh++)
            v += scr[wh * 128 + (d >> 2) * 16 + t * 4 + (d & 3)];
        v /= degf[n];
        float rt = 0.f;
#pragma unroll
        for (int c = 0; c < 32; c++) rt += xt[t][c] * root[c * 32 + d];
        v += rt + bias[d];
        v = v >= 0.f ? v : 0.01f * v;   // LeakyReLU (both spline layers)
        out[n * 32 + d] = v;
        float s = v, s2 = v * v;
        s += __shfl_xor(s, 32); s2 += __shfl_xor(s2, 32);
        if ((tid & 63) < 32) { ldsAdd(&scr2[d], s); ldsAdd(&scr2[32 + d], s2); }
    }
    __syncthreads();
    if (tid < 64) gAdd(&stats[tid], scr2[tid]);
}

// ---------------- K5: BN apply ----------------
__global__ void k_bn(const float* __restrict__ tin, const float* __restrict__ stats,
                     const float* __restrict__ gamma, const float* __restrict__ beta,
                     float* __restrict__ xout) {
    int i = blockIdx.x * 256 + threadIdx.x;   // grid exact
    int c = i & 31;
    float mu = stats[c] * (1.f / NN);
    float var = stats[32 + c] * (1.f / NN) - mu * mu;
    float g = gamma[c] * rsqrtf(var + 1e-5f);
    xout[i] = (tin[i] - mu) * g + beta[c];
}

// ---------------- K6a: NodeFormer pass 1 ----------------
// 32 nodes/block, 256 threads: thread = (nl = tid>>3, h = tid&7)
// kvloc layout: [dh(4)][h(8)][m(32)] at dh*256+h*32+m ; ksum at 1024+h*32+m
__global__ void __launch_bounds__(256) k_nf1(
        const float* __restrict__ x, const float* __restrict__ wqkv,
        const float* __restrict__ wp, const float* __restrict__ gumbel,
        float* __restrict__ vbuf, float* __restrict__ kvg) {
    __shared__ float xl[32 * 33];
    __shared__ float kvloc[1280];
    int tid = threadIdx.x;
    for (int i = tid; i < 1280; i += 256) kvloc[i] = 0.f;
    int base = blockIdx.x * 32;
#pragma unroll
    for (int r = 0; r < 4; r++) {
        int i = r * 256 + tid;
        int gi = base * 32 + i;
        float v = (gi < NN * 32) ? x[gi] : 0.f;
        xl[(i >> 5) * 33 + (i & 31)] = v;
    }
    __syncthreads();
    int nl = tid >> 3, h = tid & 7;
    int n = base + nl;
    int act = (n < NN) ? 1 : 0;
    const float* xp = &xl[nl * 33];
    float kr0 = 0, kr1 = 0, kr2 = 0, kr3 = 0, vr0 = 0, vr1 = 0, vr2 = 0, vr3 = 0;
#pragma unroll
    for (int c = 0; c < 32; c++) {
        float xc = xp[c];
        const float4 wk4 = *(const float4*)(wqkv + 1024 + c * 32 + h * 4);
        const float4 wv4 = *(const float4*)(wqkv + 2048 + c * 32 + h * 4);
        kr0 += xc * wk4.x; kr1 += xc * wk4.y; kr2 += xc * wk4.z; kr3 += xc * wk4.w;
        vr0 += xc * wv4.x; vr1 += xc * wv4.y; vr2 += xc * wv4.z; vr3 += xc * wv4.w;
    }
    if (act) *(float4*)&vbuf[n * 32 + h * 4] = make_float4(vr0, vr1, vr2, vr3);
    const float inv_rt2 = 0.70710678118f;     // 1/DH^0.25
    const float invSqM = 0.17677669529f;      // 1/sqrt(32)
    float x0 = kr0 * inv_rt2, x1 = kr1 * inv_rt2, x2 = kr2 * inv_rt2, x3 = kr3 * inv_rt2;
    float sq = 0.5f * (x0 * x0 + x1 * x1 + x2 * x2 + x3 * x3);
    float gs = act ? (__expf(gumbel[(act ? n : 0) * 8 + h]) * invSqM) : 0.f;
    const float* wph = wp + h * 128;
    for (int mm = 0; mm < 32; mm++) {
        int m = (mm + nl + 4 * h) & 31;       // stagger: conflict-free LDS atomics
        float pr = x0 * wph[m] + x1 * wph[32 + m] + x2 * wph[64 + m] + x3 * wph[96 + m];
        float phk = __expf(pr - sq) * gs;
        ldsAdd(&kvloc[1024 + h * 32 + m], phk);
        ldsAdd(&kvloc[0 * 256 + h * 32 + m], phk * vr0);
        ldsAdd(&kvloc[1 * 256 + h * 32 + m], phk * vr1);
        ldsAdd(&kvloc[2 * 256 + h * 32 + m], phk * vr2);
        ldsAdd(&kvloc[3 * 256 + h * 32 + m], phk * vr3);
    }
    __syncthreads();
    for (int i = tid; i < 1280; i += 256) gAdd(&kvg[i], kvloc[i]);
}

// ---------------- K6b: NodeFormer pass 2 ----------------
__global__ void __launch_bounds__(256) k_nf2(
        const float* __restrict__ x, const float* __restrict__ wqkv,
        const float* __restrict__ wp, const float* __restrict__ brel,
        const float* __restrict__ wo, const float* __restrict__ bo,
        const float* __restrict__ kvg, const int* __restrict__ rowptr,
        const float4* __restrict__ sedge, const float* __restrict__ degf,
        const float* __restrict__ vbuf, int do_leaky,
        float* __restrict__ out, float* __restrict__ stats) {
    __shared__ float xl[32 * 33];
    __shared__ float ylds[32 * 33];
    __shared__ float scr2[64];
    int tid = threadIdx.x;
    if (tid < 64) scr2[tid] = 0.f;
    int base = blockIdx.x * 32;
#pragma unroll
    for (int r = 0; r < 4; r++) {
        int i = r * 256 + tid;
        int gi = base * 32 + i;
        float v = (gi < NN * 32) ? x[gi] : 0.f;
        xl[(i >> 5) * 33 + (i & 31)] = v;
    }
    __syncthreads();
    int nl = tid >> 3, h = tid & 7;
    int n = base + nl;
    int act = (n < NN) ? 1 : 0;
    int nc = act ? n : (NN - 1);
    const float* xp = &xl[nl * 33];
    float q0 = 0, q1 = 0, q2 = 0, q3 = 0;
#pragma unroll
    for (int c = 0; c < 32; c++) {
        float xc = xp[c];
        const float4 wq4 = *(const float4*)(wqkv + c * 32 + h * 4);
        q0 += xc * wq4.x; q1 += xc * wq4.y; q2 += xc * wq4.z; q3 += xc * wq4.w;
    }
    const float inv_rt2 = 0.70710678118f;
    const float invSqM = 0.17677669529f;
    float x0 = q0 * inv_rt2, x1 = q1 * inv_rt2, x2 = q2 * inv_rt2, x3 = q3 * inv_rt2;
    float sq = 0.5f * (x0 * x0 + x1 * x1 + x2 * x2 + x3 * x3);
    const float* wph = wp + h * 128;
    float den = 0.f, n0 = 0.f, n1 = 0.f, n2 = 0.f, n3 = 0.f;
    for (int m = 0; m < 32; m++) {
        float pr = x0 * wph[m] + x1 * wph[32 + m] + x2 * wph[64 + m] + x3 * wph[96 + m];
        float phq = __expf(pr - sq) * invSqM;
        den += phq * kvg[1024 + h * 32 + m];
        n0 += phq * kvg[0 * 256 + h * 32 + m];
        n1 += phq * kvg[1 * 256 + h * 32 + m];
        n2 += phq * kvg[2 * 256 + h * 32 + m];
        n3 += phq * kvg[3 * 256 + h * 32 + m];
    }
    float inv = 1.f / (den + 1e-6f);
    float y0 = n0 * inv, y1 = n1 * inv, y2 = n2 * inv, y3 = n3 * inv;
    // relational bias: 8 threads of a node each gather their head's float4
    float r0 = 0, r1 = 0, r2 = 0, r3 = 0;
    int rs = rowptr[nc];
    int re = act ? rowptr[nc + 1] : rs;
    float dn = degf[nc];
    int e = rs;
    for (; e + 2 <= re; e += 2) {
        float4 ed0 = sedge[e], ed1 = sedge[e + 1];
        int s0 = __float_as_int(ed0.x), s1 = __float_as_int(ed1.x);
        float nr0 = rsqrtf(degf[s0] * dn);
        float nr1 = rsqrtf(degf[s1] * dn);
        float4 v0 = *(const float4*)&vbuf[s0 * 32 + h * 4];
        float4 v1 = *(const float4*)&vbuf[s1 * 32 + h * 4];
        r0 += nr0 * v0.x + nr1 * v1.x;
        r1 += nr0 * v0.y + nr1 * v1.y;
        r2 += nr0 * v0.z + nr1 * v1.z;
        r3 += nr0 * v0.w + nr1 * v1.w;
    }
    for (; e < re; e++) {
        float4 ed = sedge[e];
        int s0 = __float_as_int(ed.x);
        float nr = rsqrtf(degf[s0] * dn);
        float4 v0 = *(const float4*)&vbuf[s0 * 32 + h * 4];
        r0 += nr * v0.x; r1 += nr * v0.y; r2 += nr * v0.z; r3 += nr * v0.w;
    }
    float sg = 1.f / (1.f + __expf(-brel[h]));
    y0 += sg * r0; y1 += sg * r1; y2 += sg * r2; y3 += sg * r3;
    ylds[nl * 33 + h * 4 + 0] = y0;
    ylds[nl * 33 + h * 4 + 1] = y1;
    ylds[nl * 33 + h * 4 + 2] = y2;
    ylds[nl * 33 + h * 4 + 3] = y3;
    __syncthreads();
    // output projection: thread (nl,h) computes z[d = h*4 .. h*4+3]
    const float* yp = &ylds[nl * 33];
    const float4 b4 = *(const float4*)(bo + h * 4);
    float z0 = b4.x, z1 = b4.y, z2 = b4.z, z3 = b4.w;
#pragma unroll
    for (int j = 0; j < 32; j++) {
        float yv = yp[j];
        const float4 w4 = *(const float4*)(wo + j * 32 + h * 4);
        z0 += yv * w4.x; z1 += yv * w4.y; z2 += yv * w4.z; z3 += yv * w4.w;
    }
    if (do_leaky) {
        z0 = z0 >= 0.f ? z0 : 0.01f * z0;
        z1 = z1 >= 0.f ? z1 : 0.01f * z1;
        z2 = z2 >= 0.f ? z2 : 0.01f * z2;
        z3 = z3 >= 0.f ? z3 : 0.01f * z3;
    }
    if (act) *(float4*)&out[n * 32 + h * 4] = make_float4(z0, z1, z2, z3);
    // BN stats: reduce over nl (wave lane bits 3..5), then LDS, then global
    float sv[4] = {act ? z0 : 0.f, act ? z1 : 0.f, act ? z2 : 0.f, act ? z3 : 0.f};
#pragma unroll
    for (int j = 0; j < 4; j++) {
        float s = sv[j], s2 = sv[j] * sv[j];
        s += __shfl_xor(s, 8);  s2 += __shfl_xor(s2, 8);
        s += __shfl_xor(s, 16); s2 += __shfl_xor(s2, 16);
        s += __shfl_xor(s, 32); s2 += __shfl_xor(s2, 32);
        if (((tid & 63) >> 3) == 0) {
            ldsAdd(&scr2[h * 4 + j], s);
            ldsAdd(&scr2[32 + h * 4 + j], s2);
        }
    }
    __syncthreads();
    if (tid < 64) gAdd(&stats[tid], scr2[tid]);
}

extern "C" void kernel_launch(void* const* d_in, const int* in_sizes, int n_in,
                              void* d_out, int out_size, void* d_ws, size_t ws_size,
                              hipStream_t stream) {
    (void)in_sizes; (void)n_in; (void)out_size; (void)ws_size;
    const float* x_in  = (const float*)d_in[0];
    const int*   ei    = (const int*)d_in[1];
    const float* attr  = (const float*)d_in[2];
    const float* wsp1  = (const float*)d_in[3];
    const float* root1 = (const float*)d_in[4];
    const float* bias1 = (const float*)d_in[5];
    const float* wsp2  = (const float*)d_in[6];
    const float* root2 = (const float*)d_in[7];
    const float* bias2 = (const float*)d_in[8];
    const float* gam   = (const float*)d_in[9];
    const float* bet   = (const float*)d_in[10];
    const float* w1qkv = (const float*)d_in[11];
    const float* w1p   = (const float*)d_in[12];
    const float* b1rel = (const float*)d_in[13];
    const float* w1o   = (const float*)d_in[14];
    const float* b1o   = (const float*)d_in[15];
    const float* gum1  = (const float*)d_in[16];
    const float* w2qkv = (const float*)d_in[17];
    const float* w2p   = (const float*)d_in[18];
    const float* b2rel = (const float*)d_in[19];
    const float* w2o   = (const float*)d_in[20];
    const float* b2o   = (const float*)d_in[21];
    const float* gum2  = (const float*)d_in[22];
    float* outp = (float*)d_out;

    char* wsb = (char*)d_ws;
    size_t off = 0;
    auto carve = [&](size_t bytes) -> char* {
        char* p = wsb + off;
        off += (bytes + 255) & ~(size_t)255;
        return p;
    };
    int*    cnt    = (int*)carve((size_t)NN * 4);
    float*  kvg1   = (float*)carve(1280 * 4);
    float*  kvg2   = (float*)carve(1280 * 4);
    float*  stats  = (float*)carve(256 * 4);
    size_t zero_bytes = off;                     // everything above must start at 0
    int*    rowptr = (int*)carve((size_t)(NN + 1) * 4);
    int*    fill   = (int*)carve((size_t)NN * 4);
    float*  degf   = (float*)carve((size_t)NN * 4);
    float4* sedge  = (float4*)carve((size_t)NE * 16);
    float*  vbuf   = (float*)carve((size_t)NN * 32 * 4);
    float*  xa     = (float*)carve((size_t)NN * 32 * 4);
    float*  xb     = (float*)carve((size_t)NN * 32 * 4);
    float*  tb     = (float*)carve((size_t)NN * 32 * 4);

    hipMemsetAsync(d_ws, 0, zero_bytes, stream);
    k_hist<<<NE / 256, 256, 0, stream>>>(ei, cnt);
    k_scan<<<1, 1024, 0, stream>>>(cnt, rowptr, fill, degf);
    k_scatter<<<NE / 256, 256, 0, stream>>>(ei, attr, fill, sedge);

    // layer 1: spline + leaky + BN0
    k_spline<<<NN / 4, 256, 0, stream>>>(x_in, rowptr, sedge, degf, wsp1, root1, bias1, tb, stats);
    k_bn<<<NN * 32 / 256, 256, 0, stream>>>(tb, stats, gam, bet, xa);
    // layer 2: spline + leaky + BN1
    k_spline<<<NN / 4, 256, 0, stream>>>(xa, rowptr, sedge, degf, wsp2, root2, bias2, tb, stats + 64);
    k_bn<<<NN * 32 / 256, 256, 0, stream>>>(tb, stats + 64, gam + 32, bet + 32, xb);

    int nfgrid = (NN + 31) / 32;
    // layer 3: nodeformer1 + leaky + BN2
    k_nf1<<<nfgrid, 256, 0, stream>>>(xb, w1qkv, w1p, gum1, vbuf, kvg1);
    k_nf2<<<nfgrid, 256, 0, stream>>>(xb, w1qkv, w1p, b1rel, w1o, b1o, kvg1, rowptr, sedge,
                                      degf, vbuf, 1, tb, stats + 128);
    k_bn<<<NN * 32 / 256, 256, 0, stream>>>(tb, stats + 128, gam + 64, bet + 64, xa);
    // layer 4: nodeformer2 + BN3 (no leaky)
    k_nf1<<<nfgrid, 256, 0, stream>>>(xa, w2qkv, w2p, gum2, vbuf, kvg2);
    k_nf2<<<nfgrid, 256, 0, stream>>>(xa, w2qkv, w2p, b2rel, w2o, b2o, kvg2, rowptr, sedge,
                                      degf, vbuf, 0, tb, stats + 192);
    k_bn<<<NN * 32 / 256, 256, 0, stream>>>(tb, stats + 192, gam + 96, bet + 96, outp);
}

// Round 4
// 3646.624 us; speedup vs baseline: 1.2394x; 1.0511x over previous
//
#include <hip/hip_runtime.h>
#include <hip/hip_bf16.h>

#define NN 50000      // nodes
#define NE 800000     // edges
// C=32 channels, K=64 spline kernels, H=8 heads, DH=4, M=32 features

__device__ __forceinline__ void ldsAdd(float* p, float v) {
    __hip_atomic_fetch_add(p, v, __ATOMIC_RELAXED, __HIP_MEMORY_SCOPE_WORKGROUP);
}
__device__ __forceinline__ void gAdd(float* p, float v) {
    unsafeAtomicAdd(p, v);   // global_atomic_add_f32, no CAS loop
}

// ---------------- K1: histogram of dst ----------------
__global__ void k_hist(const int* __restrict__ ei, int* __restrict__ cnt) {
    int e = blockIdx.x * 256 + threadIdx.x;   // grid exact: 3125*256 = 800000
    atomicAdd(&cnt[ei[NE + e]], 1);
}

// ---------------- K2: exclusive scan (single block, shfl-based) ----------------
__global__ void __launch_bounds__(1024) k_scan(const int* __restrict__ cnt,
                                               int* __restrict__ rowptr,
                                               int* __restrict__ fill,
                                               float* __restrict__ degf) {
    __shared__ int wsum[16];
    int tid = threadIdx.x;
    int wave = tid >> 6, lane = tid & 63;
    int carry = 0;
    for (int base = 0; base < NN; base += 8192) {
        int i0 = base + tid * 8;
        int v[8], pre[8], s = 0;
#pragma unroll
        for (int j = 0; j < 8; j++) {
            int i = i0 + j;
            v[j] = (i < NN) ? cnt[i] : 0;
            pre[j] = s; s += v[j];
        }
        int sc = s;
#pragma unroll
        for (int d = 1; d < 64; d <<= 1) {
            int t = __shfl_up(sc, d);
            if (lane >= d) sc += t;
        }
        if (lane == 63) wsum[wave] = sc;
        __syncthreads();
        int wpre = 0, total = 0;
#pragma unroll
        for (int w = 0; w < 16; w++) {
            int x = wsum[w];
            if (w < wave) wpre += x;
            total += x;
        }
        int excl = carry + wpre + (sc - s);
#pragma unroll
        for (int j = 0; j < 8; j++) {
            int i = i0 + j;
            if (i < NN) {
                int st = excl + pre[j];
                rowptr[i] = st;
                fill[i]   = st;
                degf[i]   = (float)(v[j] > 0 ? v[j] : 1);
                if (i == NN - 1) rowptr[NN] = st + v[j];
            }
        }
        carry += total;
        __syncthreads();
    }
}

// ---------------- K3: scatter edges into CSR order ----------------
__global__ void k_scatter(const int* __restrict__ ei, const float* __restrict__ attr,
                          int* __restrict__ fill, float4* __restrict__ sedge) {
    int e = blockIdx.x * 256 + threadIdx.x;
    int src = ei[e], dst = ei[NE + e];
    int pos = atomicAdd(&fill[dst], 1);
    float4 r;
    r.x = __int_as_float(src);
    r.y = attr[e * 3 + 0]; r.z = attr[e * 3 + 1]; r.w = attr[e * 3 + 2];
    sedge[pos] = r;
}

// ---------------- K4: fused SplineConv + leaky + BN-stats ----------------
// 2 nodes/block, 128 threads. LDS buf layout: [idx(64)][t(2)][c ^ ((idx&7)<<2)]
__device__ __forceinline__ void edge_proc(float* __restrict__ buf, float4 ed, int t,
                                          float xs, int ch, int hi) {
    float p0 = ed.y * 3.f, p1 = ed.z * 3.f, p2 = ed.w * 3.f;
    float f0 = fmaxf(fminf(floorf(p0), 2.f), 0.f);
    float f1 = fmaxf(fminf(floorf(p1), 2.f), 0.f);
    float f2 = fmaxf(fminf(floorf(p2), 2.f), 0.f);
    float r0 = p0 - f0, r1 = p1 - f1, r2 = p2 - f2;
    int i0 = (int)f0, i1 = (int)f1, i2 = (int)f2;
#pragma unroll
    for (int q = 0; q < 4; q++) {
        int bits = hi * 4 + q;
        int b0 = bits & 1, b1 = (bits >> 1) & 1, b2 = (bits >> 2) & 1;
        float bas = (b0 ? r0 : 1.f - r0) * (b1 ? r1 : 1.f - r1) * (b2 ? r2 : 1.f - r2);
        int idx = (i0 + b0) + 4 * (i1 + b1) + 16 * (i2 + b2);
        ldsAdd(&buf[((idx * 2 + t) << 5) + (ch ^ ((idx & 7) << 2))], bas * xs);
    }
}

__global__ void __launch_bounds__(128, 4) k_spline(
        const float* __restrict__ xin, const int* __restrict__ rowptr,
        const float4* __restrict__ sedge, const float* __restrict__ degf,
        const float* __restrict__ wsp, const float* __restrict__ root,
        const float* __restrict__ bias, float* __restrict__ out,
        float* __restrict__ stats) {
    __shared__ __align__(16) float buf[4096];   // 64k * 2t * 32c = 16 KB
    __shared__ __align__(16) float xt[2][32];
    __shared__ __align__(16) float scr[512];    // [wave*4+hf (8)][d8(8)][t(2)][4]
    __shared__ float scr2[64];
    int tid = threadIdx.x;
    int wave = tid >> 6, lane = tid & 63;
    for (int i = tid; i < 4096; i += 128) buf[i] = 0.f;
    int nb = blockIdx.x * 2;                    // NN % 2 == 0
    if (tid < 64) {
        int t = tid >> 5, c = tid & 31;
        xt[t][c] = xin[(nb + t) * 32 + c];
    }
    __syncthreads();
    // -------- phase A: wave w owns node nb+w, 4-batched edge loop --------
    {
        int n = nb + wave;
        int rs = rowptr[n], re = rowptr[n + 1];
        int ch = lane & 31, hi = lane >> 5;
        int e = rs;
        for (; e + 4 <= re; e += 4) {
            float4 e0 = sedge[e + 0];
            float4 e1 = sedge[e + 1];
            float4 e2 = sedge[e + 2];
            float4 e3 = sedge[e + 3];
            float xs0 = xin[__float_as_int(e0.x) * 32 + ch];
            float xs1 = xin[__float_as_int(e1.x) * 32 + ch];
            float xs2 = xin[__float_as_int(e2.x) * 32 + ch];
            float xs3 = xin[__float_as_int(e3.x) * 32 + ch];
            edge_proc(buf, e0, wave, xs0, ch, hi);
            edge_proc(buf, e1, wave, xs1, ch, hi);
            edge_proc(buf, e2, wave, xs2, ch, hi);
            edge_proc(buf, e3, wave, xs3, ch, hi);
        }
        for (; e < re; e++) {
            float4 ed = sedge[e];
            float xs = xin[__float_as_int(ed.x) * 32 + ch];
            edge_proc(buf, ed, wave, xs, ch, hi);
        }
    }
    __syncthreads();
    // -------- phase B: einsum nkc,kcd -> nd ; k = hf*16 + wave*8 + kk --------
    int kk = lane >> 3, d8 = lane & 7;
    float4 acc[4][2];
#pragma unroll
    for (int hf = 0; hf < 4; hf++)
#pragma unroll
        for (int t = 0; t < 2; t++) acc[hf][t] = make_float4(0.f, 0.f, 0.f, 0.f);
#pragma unroll
    for (int hf = 0; hf < 4; hf++) {
        int k = hf * 16 + wave * 8 + kk;        // k&7 == kk
        const float* wk = wsp + k * 1024;
#pragma unroll
        for (int c4 = 0; c4 < 8; c4++) {
            float4 wv0 = *(const float4*)(wk + (c4 * 4 + 0) * 32 + d8 * 4);
            float4 wv1 = *(const float4*)(wk + (c4 * 4 + 1) * 32 + d8 * 4);
            float4 wv2 = *(const float4*)(wk + (c4 * 4 + 2) * 32 + d8 * 4);
            float4 wv3 = *(const float4*)(wk + (c4 * 4 + 3) * 32 + d8 * 4);
            int cp = (c4 ^ kk) << 2;
            const float* bp = &buf[(k * 2) << 5];
#pragma unroll
            for (int t = 0; t < 2; t++) {
                float4 bv = *(const float4*)(bp + (t << 5) + cp);
                acc[hf][t].x += bv.x * wv0.x + bv.y * wv1.x + bv.z * wv2.x + bv.w * wv3.x;
                acc[hf][t].y += bv.x * wv0.y + bv.y * wv1.y + bv.z * wv2.y + bv.w * wv3.y;
                acc[hf][t].z += bv.x * wv0.z + bv.y * wv1.z + bv.z * wv2.z + bv.w * wv3.z;
                acc[hf][t].w += bv.x * wv0.w + bv.y * wv1.w + bv.z * wv2.w + bv.w * wv3.w;
            }
        }
    }
#pragma unroll
    for (int hf = 0; hf < 4; hf++)
#pragma unroll
    for (int t = 0; t < 2; t++) {
        float sx = acc[hf][t].x, sy = acc[hf][t].y, sz = acc[hf][t].z, sw = acc[hf][t].w;
        sx += __shfl_xor(sx, 8);  sy += __shfl_xor(sy, 8);  sz += __shfl_xor(sz, 8);  sw += __shfl_xor(sw, 8);
        sx += __shfl_xor(sx, 16); sy += __shfl_xor(sy, 16); sz += __shfl_xor(sz, 16); sw += __shfl_xor(sw, 16);
        sx += __shfl_xor(sx, 32); sy += __shfl_xor(sy, 32); sz += __shfl_xor(sz, 32); sw += __shfl_xor(sw, 32);
        acc[hf][t] = make_float4(sx, sy, sz, sw);
    }
    if (kk == 0) {
#pragma unroll
        for (int hf = 0; hf < 4; hf++)
#pragma unroll
        for (int t = 0; t < 2; t++)
            *(float4*)&scr[(wave * 4 + hf) * 64 + d8 * 8 + t * 4] = acc[hf][t];
    }
    __syncthreads();
    if (tid < 64) {
        int t = tid >> 5, d = tid & 31;
        int n = nb + t;
        float v = 0.f;
#pragma unroll
        for (int g = 0; g < 8; g++)
            v += scr[g * 64 + (d >> 2) * 8 + t * 4 + (d & 3)];
        v /= degf[n];
        float rt = 0.f;
#pragma unroll
        for (int c = 0; c < 32; c++) rt += xt[t][c] * root[c * 32 + d];
        v += rt + bias[d];
        v = v >= 0.f ? v : 0.01f * v;   // LeakyReLU (both spline layers)
        out[n * 32 + d] = v;
        float s = v, s2 = v * v;
        s += __shfl_xor(s, 32); s2 += __shfl_xor(s2, 32);
        if (tid < 32) { scr2[d] = s; scr2[32 + d] = s2; }  // single wave: plain writes
    }
    __syncthreads();
    // replicated stats: spreads atomics over 64 slots (no hot lines)
    if (tid < 64) gAdd(&stats[(blockIdx.x & 63) * 64 + tid], scr2[tid]);
}

// ---------------- K4b: fold 64 replicated stat slots ----------------
__global__ void k_red(const float* __restrict__ stats, float* __restrict__ fin) {
    int j = threadIdx.x;   // 64 threads
    float s = 0.f;
#pragma unroll 8
    for (int r = 0; r < 64; r++) s += stats[r * 64 + j];
    fin[j] = s;
}

// ---------------- K5: BN apply ----------------
__global__ void k_bn(const float* __restrict__ tin, const float* __restrict__ fin,
                     const float* __restrict__ gamma, const float* __restrict__ beta,
                     float* __restrict__ xout) {
    int i = blockIdx.x * 256 + threadIdx.x;   // grid exact
    int c = i & 31;
    float mu = fin[c] * (1.f / NN);
    float var = fin[32 + c] * (1.f / NN) - mu * mu;
    float g = gamma[c] * rsqrtf(var + 1e-5f);
    xout[i] = (tin[i] - mu) * g + beta[c];
}

// ---------------- K6a: NodeFormer pass 1 ----------------
// 32 nodes/block, 256 threads: thread = (nl = tid>>3, h = tid&7)
// kvloc layout: [dh(4)][h(8)][m(32)] at dh*256+h*32+m ; ksum at 1024+h*32+m
__global__ void __launch_bounds__(256) k_nf1(
        const float* __restrict__ x, const float* __restrict__ wqkv,
        const float* __restrict__ wp, const float* __restrict__ gumbel,
        float* __restrict__ vbuf, float* __restrict__ kvg) {
    __shared__ float xl[32 * 33];
    __shared__ float kvloc[1280];
    int tid = threadIdx.x;
    for (int i = tid; i < 1280; i += 256) kvloc[i] = 0.f;
    int base = blockIdx.x * 32;
#pragma unroll
    for (int r = 0; r < 4; r++) {
        int i = r * 256 + tid;
        int gi = base * 32 + i;
        float v = (gi < NN * 32) ? x[gi] : 0.f;
        xl[(i >> 5) * 33 + (i & 31)] = v;
    }
    __syncthreads();
    int nl = tid >> 3, h = tid & 7;
    int n = base + nl;
    int act = (n < NN) ? 1 : 0;
    const float* xp = &xl[nl * 33];
    float kr0 = 0, kr1 = 0, kr2 = 0, kr3 = 0, vr0 = 0, vr1 = 0, vr2 = 0, vr3 = 0;
#pragma unroll
    for (int c = 0; c < 32; c++) {
        float xc = xp[c];
        const float4 wk4 = *(const float4*)(wqkv + 1024 + c * 32 + h * 4);
        const float4 wv4 = *(const float4*)(wqkv + 2048 + c * 32 + h * 4);
        kr0 += xc * wk4.x; kr1 += xc * wk4.y; kr2 += xc * wk4.z; kr3 += xc * wk4.w;
        vr0 += xc * wv4.x; vr1 += xc * wv4.y; vr2 += xc * wv4.z; vr3 += xc * wv4.w;
    }
    if (act) *(float4*)&vbuf[n * 32 + h * 4] = make_float4(vr0, vr1, vr2, vr3);
    const float inv_rt2 = 0.70710678118f;     // 1/DH^0.25
    const float invSqM = 0.17677669529f;      // 1/sqrt(32)
    float x0 = kr0 * inv_rt2, x1 = kr1 * inv_rt2, x2 = kr2 * inv_rt2, x3 = kr3 * inv_rt2;
    float sq = 0.5f * (x0 * x0 + x1 * x1 + x2 * x2 + x3 * x3);
    float gs = act ? (__expf(gumbel[(act ? n : 0) * 8 + h]) * invSqM) : 0.f;
    const float* wph = wp + h * 128;
    for (int mm = 0; mm < 32; mm++) {
        int m = (mm + nl + 4 * h) & 31;       // stagger: ≤2-way LDS banks
        float pr = x0 * wph[m] + x1 * wph[32 + m] + x2 * wph[64 + m] + x3 * wph[96 + m];
        float phk = __expf(pr - sq) * gs;
        ldsAdd(&kvloc[1024 + h * 32 + m], phk);
        ldsAdd(&kvloc[0 * 256 + h * 32 + m], phk * vr0);
        ldsAdd(&kvloc[1 * 256 + h * 32 + m], phk * vr1);
        ldsAdd(&kvloc[2 * 256 + h * 32 + m], phk * vr2);
        ldsAdd(&kvloc[3 * 256 + h * 32 + m], phk * vr3);
    }
    __syncthreads();
    // replicated kvg: 8 slots
    float* kvr = kvg + (blockIdx.x & 7) * 1280;
    for (int i = tid; i < 1280; i += 256) gAdd(&kvr[i], kvloc[i]);
}

// ---------------- K6b: NodeFormer pass 2 ----------------
__global__ void __launch_bounds__(256) k_nf2(
        const float* __restrict__ x, const float* __restrict__ wqkv,
        const float* __restrict__ wp, const float* __restrict__ brel,
        const float* __restrict__ wo, const float* __restrict__ bo,
        const float* __restrict__ kvg, const int* __restrict__ rowptr,
        const float4* __restrict__ sedge, const float* __restrict__ degf,
        const float* __restrict__ vbuf, int do_leaky,
        float* __restrict__ out, float* __restrict__ stats) {
    __shared__ float xl[32 * 33];
    __shared__ float ylds[32 * 33];
    __shared__ float kvs[1280];
    __shared__ float scr2[64];
    int tid = threadIdx.x;
    if (tid < 64) scr2[tid] = 0.f;
    int base = blockIdx.x * 32;
#pragma unroll
    for (int r = 0; r < 4; r++) {
        int i = r * 256 + tid;
        int gi = base * 32 + i;
        float v = (gi < NN * 32) ? x[gi] : 0.f;
        xl[(i >> 5) * 33 + (i & 31)] = v;
    }
    // stage kv summary: sum the 8 replicated slots into LDS
    for (int i = tid; i < 1280; i += 256) {
        float s = 0.f;
#pragma unroll
        for (int r = 0; r < 8; r++) s += kvg[r * 1280 + i];
        kvs[i] = s;
    }
    __syncthreads();
    int nl = tid >> 3, h = tid & 7;
    int n = base + nl;
    int act = (n < NN) ? 1 : 0;
    int nc = act ? n : (NN - 1);
    const float* xp = &xl[nl * 33];
    float q0 = 0, q1 = 0, q2 = 0, q3 = 0;
#pragma unroll
    for (int c = 0; c < 32; c++) {
        float xc = xp[c];
        const float4 wq4 = *(const float4*)(wqkv + c * 32 + h * 4);
        q0 += xc * wq4.x; q1 += xc * wq4.y; q2 += xc * wq4.z; q3 += xc * wq4.w;
    }
    const float inv_rt2 = 0.70710678118f;
    const float invSqM = 0.17677669529f;
    float x0 = q0 * inv_rt2, x1 = q1 * inv_rt2, x2 = q2 * inv_rt2, x3 = q3 * inv_rt2;
    float sq = 0.5f * (x0 * x0 + x1 * x1 + x2 * x2 + x3 * x3);
    const float* wph = wp + h * 128;
    float den = 0.f, n0 = 0.f, n1 = 0.f, n2 = 0.f, n3 = 0.f;
    for (int mm = 0; mm < 32; mm++) {
        int m = (mm + 4 * h) & 31;            // h-stagger: LDS bank-clean
        float pr = x0 * wph[m] + x1 * wph[32 + m] + x2 * wph[64 + m] + x3 * wph[96 + m];
        float phq = __expf(pr - sq) * invSqM;
        den += phq * kvs[1024 + h * 32 + m];
        n0 += phq * kvs[0 * 256 + h * 32 + m];
        n1 += phq * kvs[1 * 256 + h * 32 + m];
        n2 += phq * kvs[2 * 256 + h * 32 + m];
        n3 += phq * kvs[3 * 256 + h * 32 + m];
    }
    float inv = 1.f / (den + 1e-6f);
    float y0 = n0 * inv, y1 = n1 * inv, y2 = n2 * inv, y3 = n3 * inv;
    // relational bias: 8 threads of a node each gather their head's float4
    float r0 = 0, r1 = 0, r2 = 0, r3 = 0;
    int rs = rowptr[nc];
    int re = act ? rowptr[nc + 1] : rs;
    float dn = degf[nc];
    int e = rs;
    for (; e + 2 <= re; e += 2) {
        float4 ed0 = sedge[e], ed1 = sedge[e + 1];
        int s0 = __float_as_int(ed0.x), s1 = __float_as_int(ed1.x);
        float nr0 = rsqrtf(degf[s0] * dn);
        float nr1 = rsqrtf(degf[s1] * dn);
        float4 v0 = *(const float4*)&vbuf[s0 * 32 + h * 4];
        float4 v1 = *(const float4*)&vbuf[s1 * 32 + h * 4];
        r0 += nr0 * v0.x + nr1 * v1.x;
        r1 += nr0 * v0.y + nr1 * v1.y;
        r2 += nr0 * v0.z + nr1 * v1.z;
        r3 += nr0 * v0.w + nr1 * v1.w;
    }
    for (; e < re; e++) {
        float4 ed = sedge[e];
        int s0 = __float_as_int(ed.x);
        float nr = rsqrtf(degf[s0] * dn);
        float4 v0 = *(const float4*)&vbuf[s0 * 32 + h * 4];
        r0 += nr * v0.x; r1 += nr * v0.y; r2 += nr * v0.z; r3 += nr * v0.w;
    }
    float sg = 1.f / (1.f + __expf(-brel[h]));
    y0 += sg * r0; y1 += sg * r1; y2 += sg * r2; y3 += sg * r3;
    ylds[nl * 33 + h * 4 + 0] = y0;
    ylds[nl * 33 + h * 4 + 1] = y1;
    ylds[nl * 33 + h * 4 + 2] = y2;
    ylds[nl * 33 + h * 4 + 3] = y3;
    __syncthreads();
    // output projection: thread (nl,h) computes z[d = h*4 .. h*4+3]
    const float* yp = &ylds[nl * 33];
    const float4 b4 = *(const float4*)(bo + h * 4);
    float z0 = b4.x, z1 = b4.y, z2 = b4.z, z3 = b4.w;
#pragma unroll
    for (int j = 0; j < 32; j++) {
        float yv = yp[j];
        const float4 w4 = *(const float4*)(wo + j * 32 + h * 4);
        z0 += yv * w4.x; z1 += yv * w4.y; z2 += yv * w4.z; z3 += yv * w4.w;
    }
    if (do_leaky) {
        z0 = z0 >= 0.f ? z0 : 0.01f * z0;
        z1 = z1 >= 0.f ? z1 : 0.01f * z1;
        z2 = z2 >= 0.f ? z2 : 0.01f * z2;
        z3 = z3 >= 0.f ? z3 : 0.01f * z3;
    }
    if (act) *(float4*)&out[n * 32 + h * 4] = make_float4(z0, z1, z2, z3);
    // BN stats: reduce over nl (wave lane bits 3..5), then LDS, then global
    float sv[4] = {act ? z0 : 0.f, act ? z1 : 0.f, act ? z2 : 0.f, act ? z3 : 0.f};
#pragma unroll
    for (int j = 0; j < 4; j++) {
        float s = sv[j], s2 = sv[j] * sv[j];
        s += __shfl_xor(s, 8);  s2 += __shfl_xor(s2, 8);
        s += __shfl_xor(s, 16); s2 += __shfl_xor(s2, 16);
        s += __shfl_xor(s, 32); s2 += __shfl_xor(s2, 32);
        if (((tid & 63) >> 3) == 0) {
            ldsAdd(&scr2[h * 4 + j], s);
            ldsAdd(&scr2[32 + h * 4 + j], s2);
        }
    }
    __syncthreads();
    if (tid < 64) gAdd(&stats[(blockIdx.x & 63) * 64 + tid], scr2[tid]);
}

extern "C" void kernel_launch(void* const* d_in, const int* in_sizes, int n_in,
                              void* d_out, int out_size, void* d_ws, size_t ws_size,
                              hipStream_t stream) {
    (void)in_sizes; (void)n_in; (void)out_size; (void)ws_size;
    const float* x_in  = (const float*)d_in[0];
    const int*   ei    = (const int*)d_in[1];
    const float* attr  = (const float*)d_in[2];
    const float* wsp1  = (const float*)d_in[3];
    const float* root1 = (const float*)d_in[4];
    const float* bias1 = (const float*)d_in[5];
    const float* wsp2  = (const float*)d_in[6];
    const float* root2 = (const float*)d_in[7];
    const float* bias2 = (const float*)d_in[8];
    const float* gam   = (const float*)d_in[9];
    const float* bet   = (const float*)d_in[10];
    const float* w1qkv = (const float*)d_in[11];
    const float* w1p   = (const float*)d_in[12];
    const float* b1rel = (const float*)d_in[13];
    const float* w1o   = (const float*)d_in[14];
    const float* b1o   = (const float*)d_in[15];
    const float* gum1  = (const float*)d_in[16];
    const float* w2qkv = (const float*)d_in[17];
    const float* w2p   = (const float*)d_in[18];
    const float* b2rel = (const float*)d_in[19];
    const float* w2o   = (const float*)d_in[20];
    const float* b2o   = (const float*)d_in[21];
    const float* gum2  = (const float*)d_in[22];
    float* outp = (float*)d_out;

    char* wsb = (char*)d_ws;
    size_t off = 0;
    auto carve = [&](size_t bytes) -> char* {
        char* p = wsb + off;
        off += (bytes + 255) & ~(size_t)255;
        return p;
    };
    int*    cnt    = (int*)carve((size_t)NN * 4);
    float*  kvg1   = (float*)carve(8 * 1280 * 4);
    float*  kvg2   = (float*)carve(8 * 1280 * 4);
    float*  stats  = (float*)carve(4 * 64 * 64 * 4);    // [layer][64 reps][64]
    size_t zero_bytes = off;                     // everything above must start at 0
    float*  fin    = (float*)carve(4 * 64 * 4);  // folded stats per layer
    int*    rowptr = (int*)carve((size_t)(NN + 1) * 4);
    int*    fill   = (int*)carve((size_t)NN * 4);
    float*  degf   = (float*)carve((size_t)NN * 4);
    float4* sedge  = (float4*)carve((size_t)NE * 16);
    float*  vbuf   = (float*)carve((size_t)NN * 32 * 4);
    float*  xa     = (float*)carve((size_t)NN * 32 * 4);
    float*  xb     = (float*)carve((size_t)NN * 32 * 4);
    float*  tb     = (float*)carve((size_t)NN * 32 * 4);

    hipMemsetAsync(d_ws, 0, zero_bytes, stream);
    k_hist<<<NE / 256, 256, 0, stream>>>(ei, cnt);
    k_scan<<<1, 1024, 0, stream>>>(cnt, rowptr, fill, degf);
    k_scatter<<<NE / 256, 256, 0, stream>>>(ei, attr, fill, sedge);

    // layer 1: spline + leaky + BN0
    k_spline<<<NN / 2, 128, 0, stream>>>(x_in, rowptr, sedge, degf, wsp1, root1, bias1, tb, stats);
    k_red<<<1, 64, 0, stream>>>(stats, fin);
    k_bn<<<NN * 32 / 256, 256, 0, stream>>>(tb, fin, gam, bet, xa);
    // layer 2: spline + leaky + BN1
    k_spline<<<NN / 2, 128, 0, stream>>>(xa, rowptr, sedge, degf, wsp2, root2, bias2, tb, stats + 4096);
    k_red<<<1, 64, 0, stream>>>(stats + 4096, fin + 64);
    k_bn<<<NN * 32 / 256, 256, 0, stream>>>(tb, fin + 64, gam + 32, bet + 32, xb);

    int nfgrid = (NN + 31) / 32;
    // layer 3: nodeformer1 + leaky + BN2
    k_nf1<<<nfgrid, 256, 0, stream>>>(xb, w1qkv, w1p, gum1, vbuf, kvg1);
    k_nf2<<<nfgrid, 256, 0, stream>>>(xb, w1qkv, w1p, b1rel, w1o, b1o, kvg1, rowptr, sedge,
                                      degf, vbuf, 1, tb, stats + 8192);
    k_red<<<1, 64, 0, stream>>>(stats + 8192, fin + 128);
    k_bn<<<NN * 32 / 256, 256, 0, stream>>>(tb, fin + 128, gam + 64, bet + 64, xa);
    // layer 4: nodeformer2 + BN3 (no leaky)
    k_nf1<<<nfgrid, 256, 0, stream>>>(xa, w2qkv, w2p, gum2, vbuf, kvg2);
    k_nf2<<<nfgrid, 256, 0, stream>>>(xa, w2qkv, w2p, b2rel, w2o, b2o, kvg2, rowptr, sedge,
                                      degf, vbuf, 0, tb, stats + 12288);
    k_red<<<1, 64, 0, stream>>>(stats + 12288, fin + 192);
    k_bn<<<NN * 32 / 256, 256, 0, stream>>>(tb, fin + 192, gam + 96, bet + 96, outp);
}